// Round 6
// baseline (406.650 us; speedup 1.0000x reference)
//
#include <hip/hip_runtime.h>
#include <math.h>

#define NEG_SLOPE 0.2f
#define EPSF 1e-16f

constexpr int FIN = 128;
constexpr int H   = 64;
constexpr int C   = 2;
constexpr int BSHIFT = 10;              // nodes per bucket = 1024
constexpr int NBUCK_MAX = 1024;         // supports N <= 1M
constexpr int CHUNK = 4096;             // edges per stage block

typedef short v8s __attribute__((ext_vector_type(8)));
typedef float v4f __attribute__((ext_vector_type(4)));
typedef unsigned short u16;

// round-to-nearest-even fp32 -> bf16 split (hi + lo captures ~17 mantissa bits)
__device__ inline void split_bf16(float v, u16& hi, u16& lo) {
    unsigned u = __float_as_uint(v);
    unsigned r = (u + 0x7FFFu + ((u >> 16) & 1u)) >> 16;
    hi = (u16)r;
    float hf = __uint_as_float(r << 16);
    float l = v - hf;
    unsigned ul = __float_as_uint(l);
    lo = (u16)((ul + 0x7FFFu + ((ul >> 16) & 1u)) >> 16);
}

__device__ inline u16 to_bf16(float v) {
    unsigned u = __float_as_uint(v);
    return (u16)((u + 0x7FFFu + ((u >> 16) & 1u)) >> 16);
}
__device__ inline float from_bf16(u16 h) {
    return __uint_as_float((unsigned)h << 16);
}

// ---------- scalar precompute ----------
__global__ void ea_sum_kernel(const float* __restrict__ ea, int E, float* __restrict__ out) {
    float acc = 0.f;
    for (int i = blockIdx.x * blockDim.x + threadIdx.x; i < E; i += gridDim.x * blockDim.x)
        acc += ea[i];
    for (int off = 32; off; off >>= 1) acc += __shfl_down(acc, off, 64);
    __shared__ float wsum[4];
    int lane = threadIdx.x & 63, wv = threadIdx.x >> 6;
    if (lane == 0) wsum[wv] = acc;
    __syncthreads();
    if (threadIdx.x == 0) atomicAdd(out, wsum[0] + wsum[1] + wsum[2] + wsum[3]);
}

__global__ void scalars_kernel(const float* __restrict__ sum_ea, int E,
                               const float* __restrict__ W_edge1, const float* __restrict__ att_edge1,
                               const float* __restrict__ W_edge2, const float* __restrict__ att_edge2,
                               float* __restrict__ out3) {
    if (threadIdx.x == 0) {
        float m = *sum_ea / (float)E;
        float c1 = 0.f;
        for (int i = 0; i < H; i++) c1 += W_edge1[i] * att_edge1[i];
        float c2 = 0.f;
        for (int i = 0; i < C; i++) c2 += W_edge2[i] * att_edge2[i];
        out3[0] = m; out3[1] = c1; out3[2] = c2;
    }
}

// ---------- W1 prep: transpose to [f][k] + split to bf16 hi/lo ----------
__global__ void wprep_kernel(const float* __restrict__ W1,
                             u16* __restrict__ Wt_hi, u16* __restrict__ Wt_lo) {
    int idx = blockIdx.x * 256 + threadIdx.x;
    if (idx >= FIN * H) return;
    int k = idx >> 6, f = idx & 63;           // W1 is [k][f]
    u16 h, l;
    split_bf16(W1[idx], h, l);
    Wt_hi[f * FIN + k] = h;
    Wt_lo[f * FIN + k] = l;
}

// ---------- P0: bucket counts (LDS-aggregated) ----------
__global__ __launch_bounds__(256) void bcount_kernel(const int* __restrict__ dst, int E,
                                                     int* __restrict__ bcount, int NBUCK) {
    __shared__ int lh[NBUCK_MAX];
    for (int i = threadIdx.x; i < NBUCK_MAX; i += 256) lh[i] = 0;
    __syncthreads();
    for (int e = blockIdx.x * 256 + threadIdx.x; e < E; e += gridDim.x * 256)
        atomicAdd(&lh[dst[e] >> BSHIFT], 1);
    __syncthreads();
    for (int i = threadIdx.x; i < NBUCK; i += 256)
        if (lh[i]) atomicAdd(&bcount[i], lh[i]);
}

// ---------- P1: scan bucket counts -> bbase, bcursor ----------
__global__ __launch_bounds__(1024) void bscan_kernel(const int* __restrict__ bcount, int NBUCK, int E,
                                                     int* __restrict__ bbase, int* __restrict__ bcursor,
                                                     int* __restrict__ rowN) {
    __shared__ int sh[1024];
    int t = threadIdx.x;
    int v = (t < NBUCK) ? bcount[t] : 0;
    sh[t] = v;
    __syncthreads();
    for (int off = 1; off < 1024; off <<= 1) {
        int u = (t >= off) ? sh[t - off] : 0;
        __syncthreads();
        sh[t] += u;
        __syncthreads();
    }
    if (t < NBUCK) { bbase[t] = sh[t] - v; bcursor[t] = sh[t] - v; }
    if (t == 0) { bbase[NBUCK] = E; *rowN = E; }
}

// ---------- P2: stage edges into bucket-major order (coalesced runs) ----------
__global__ __launch_bounds__(256) void stage_kernel(
        const int* __restrict__ src, const int* __restrict__ dst, const float* __restrict__ ea,
        int E, int* __restrict__ bcursor, int2* __restrict__ staging, int NBUCK) {
    __shared__ int   cur[NBUCK_MAX];
    __shared__ int   gofs[NBUCK_MAX];
    __shared__ int2  sbuf[CHUNK];
    __shared__ short sbkt[CHUNK];
    __shared__ int   red[256];
    int t = threadIdx.x;
    int base = blockIdx.x * CHUNK;
    int cnt = min(CHUNK, E - base);
    for (int i = t; i < NBUCK_MAX; i += 256) cur[i] = 0;
    __syncthreads();
    for (int i = t; i < cnt; i += 256)
        atomicAdd(&cur[dst[base + i] >> BSHIFT], 1);
    __syncthreads();
    int i0 = t * 4;
    int v0 = cur[i0], v1 = cur[i0 + 1], v2 = cur[i0 + 2], v3 = cur[i0 + 3];
    int s = v0 + v1 + v2 + v3;
    red[t] = s;
    __syncthreads();
    for (int off = 1; off < 256; off <<= 1) {
        int u = (t >= off) ? red[t - off] : 0;
        __syncthreads();
        red[t] += u;
        __syncthreads();
    }
    int run = red[t] - s;
    __syncthreads();
    int p = run;
    if (v0) gofs[i0]     = atomicAdd(&bcursor[i0],     v0) - p;
    cur[i0] = p; p += v0;
    if (v1) gofs[i0 + 1] = atomicAdd(&bcursor[i0 + 1], v1) - p;
    cur[i0 + 1] = p; p += v1;
    if (v2) gofs[i0 + 2] = atomicAdd(&bcursor[i0 + 2], v2) - p;
    cur[i0 + 2] = p; p += v2;
    if (v3) gofs[i0 + 3] = atomicAdd(&bcursor[i0 + 3], v3) - p;
    cur[i0 + 3] = p; p += v3;
    __syncthreads();
    for (int i = t; i < cnt; i += 256) {
        int e = base + i;
        int d = dst[e];
        int b = d >> BSHIFT;
        int slot = atomicAdd(&cur[b], 1);
        sbuf[slot] = make_int2(src[e] | ((d & ((1 << BSHIFT) - 1)) << 20), __float_as_int(ea[e]));
        sbkt[slot] = (short)b;
    }
    __syncthreads();
    for (int j = t; j < cnt; j += 256)
        staging[gofs[sbkt[j]] + j] = sbuf[j];
}

// ---------- layer 1 GEMM via split-bf16 MFMA; h1 stored as bf16 ----------
__global__ __launch_bounds__(256) void gemm1_mfma_kernel(
        const float* __restrict__ x,
        const u16* __restrict__ Wt_hi, const u16* __restrict__ Wt_lo,
        const float* __restrict__ att_src, const float* __restrict__ att_dst,
        u16* __restrict__ h1b, float* __restrict__ a_s, float* __restrict__ a_d, int N) {
    int w = threadIdx.x >> 6, lane = threadIdx.x & 63;
    int m = lane & 15, q = lane >> 4;
    int base = blockIdx.x * 64 + w * 16;
    int nodeA = base + m;
    bool inA = nodeA < N;
    const float* xrow = x + (size_t)nodeA * FIN;

    v8s ah[4], al[4];
    #pragma unroll
    for (int kt = 0; kt < 4; kt++) {
        float xv[8];
        if (inA) {
            const float4* p = (const float4*)(xrow + kt * 32 + q * 8);
            float4 u0 = p[0], u1 = p[1];
            xv[0] = u0.x; xv[1] = u0.y; xv[2] = u0.z; xv[3] = u0.w;
            xv[4] = u1.x; xv[5] = u1.y; xv[6] = u1.z; xv[7] = u1.w;
        } else {
            #pragma unroll
            for (int j = 0; j < 8; j++) xv[j] = 0.f;
        }
        #pragma unroll
        for (int j = 0; j < 8; j++) {
            u16 hb, lb;
            split_bf16(xv[j], hb, lb);
            ah[kt][j] = (short)hb;
            al[kt][j] = (short)lb;
        }
    }

    float ps[4] = {0.f, 0.f, 0.f, 0.f};
    float pd[4] = {0.f, 0.f, 0.f, 0.f};
    #pragma unroll
    for (int ft = 0; ft < 4; ft++) {
        v4f acc = {0.f, 0.f, 0.f, 0.f};
        const u16* bh_base = Wt_hi + (ft * 16 + m) * FIN + q * 8;
        const u16* bl_base = Wt_lo + (ft * 16 + m) * FIN + q * 8;
        #pragma unroll
        for (int kt = 0; kt < 4; kt++) {
            v8s bh = *(const v8s*)(bh_base + kt * 32);
            v8s bl = *(const v8s*)(bl_base + kt * 32);
            acc = __builtin_amdgcn_mfma_f32_16x16x32_bf16(ah[kt], bh, acc, 0, 0, 0);
            acc = __builtin_amdgcn_mfma_f32_16x16x32_bf16(al[kt], bh, acc, 0, 0, 0);
            acc = __builtin_amdgcn_mfma_f32_16x16x32_bf16(ah[kt], bl, acc, 0, 0, 0);
        }
        int f = ft * 16 + m;               // C col
        float asf = att_src[f], adf = att_dst[f];
        #pragma unroll
        for (int r = 0; r < 4; r++) {      // C row = q*4 + r
            int node = base + q * 4 + r;
            if (node < N) h1b[(size_t)node * H + f] = to_bf16(acc[r]);
            ps[r] += acc[r] * asf;
            pd[r] += acc[r] * adf;
        }
    }
    #pragma unroll
    for (int msk = 1; msk < 16; msk <<= 1) {
        #pragma unroll
        for (int r = 0; r < 4; r++) {
            ps[r] += __shfl_xor(ps[r], msk, 64);
            pd[r] += __shfl_xor(pd[r], msk, 64);
        }
    }
    if (m == 0) {
        #pragma unroll
        for (int r = 0; r < 4; r++) {
            int node = base + q * 4 + r;
            if (node < N) { a_s[node] = ps[r]; a_d[node] = pd[r]; }
        }
    }
}

// ---------- P3: per-bucket finalize: CSR rows + scatter + INLINE ex1 precompute ----------
__global__ __launch_bounds__(256) void bfin_kernel(
        const int2* __restrict__ staging, const int* __restrict__ bbase,
        const float* __restrict__ scal,
        const float* __restrict__ a_s1, const float* __restrict__ a_d1,
        int* __restrict__ row, int2* __restrict__ sedge, float* __restrict__ sea2, int N) {
    __shared__ int nh[NBUCK_MAX];
    __shared__ int red[256];
    int b = blockIdx.x, t = threadIdx.x;
    int beg = bbase[b], end = bbase[b + 1];
    int node0 = b << BSHIFT;
    float c1 = scal[1];
    for (int i = t; i < NBUCK_MAX; i += 256) nh[i] = 0;
    __syncthreads();
    for (int i = beg + t; i < end; i += 256)
        atomicAdd(&nh[(unsigned)staging[i].x >> 20], 1);
    __syncthreads();
    int i0 = t * 4;
    int v0 = nh[i0], v1 = nh[i0 + 1], v2 = nh[i0 + 2], v3 = nh[i0 + 3];
    int s = v0 + v1 + v2 + v3;
    red[t] = s;
    __syncthreads();
    for (int off = 1; off < 256; off <<= 1) {
        int u = (t >= off) ? red[t - off] : 0;
        __syncthreads();
        red[t] += u;
        __syncthreads();
    }
    int run = red[t] - s + beg;
    __syncthreads();
    int p = run;
    #pragma unroll
    for (int j = 0; j < 4; j++) {
        int idx = i0 + j;
        int v = (j == 0) ? v0 : (j == 1) ? v1 : (j == 2) ? v2 : v3;
        int node = node0 + idx;
        if (node < N) row[node] = p;
        nh[idx] = p;
        p += v;
    }
    __syncthreads();
    for (int i = beg + t; i < end; i += 256) {
        int2 r = staging[i];
        int dlow = (unsigned)r.x >> 20;
        int sn = r.x & 0xFFFFF;
        float eav = __int_as_float(r.y);
        float lg = a_s1[sn] + a_d1[node0 + dlow] + eav * c1;
        lg = lg > 0.f ? lg : NEG_SLOPE * lg;
        float ex = __expf(lg);
        int pos = atomicAdd(&nh[dlow], 1);
        sedge[pos] = make_int2(sn, __float_as_int(ex));
        sea2[pos] = eav;
    }
}

// ---------- layer 1 aggregation (wave per dst node; ex precomputed) + gemm2 fused ----------
__global__ __launch_bounds__(256) void agg1_kernel(
        const int* __restrict__ row, const int2* __restrict__ sedge,
        const float* __restrict__ scal,
        const float* __restrict__ a_s, const float* __restrict__ a_d,
        const u16* __restrict__ h1b,
        const float* __restrict__ bias1, const float* __restrict__ W2,
        const float* __restrict__ att_src2, const float* __restrict__ att_dst2,
        float* __restrict__ h2, float* __restrict__ a_s2, float* __restrict__ a_d2,
        int N) {
    int n = (blockIdx.x << 2) + (threadIdx.x >> 6);   // dst node
    int lane = threadIdx.x & 63;
    if (n >= N) return;
    int beg = row[n], end = row[n + 1];
    float den = 0.f, acc = 0.f;
    int i = beg;
    for (; i + 4 <= end; i += 4) {
        int2 r0 = sedge[i], r1 = sedge[i + 1], r2 = sedge[i + 2], r3 = sedge[i + 3];
        u16 g0 = h1b[(size_t)r0.x * H + lane];
        u16 g1 = h1b[(size_t)r1.x * H + lane];
        u16 g2 = h1b[(size_t)r2.x * H + lane];
        u16 g3 = h1b[(size_t)r3.x * H + lane];
        float e0 = __int_as_float(r0.y), e1 = __int_as_float(r1.y);
        float e2 = __int_as_float(r2.y), e3 = __int_as_float(r3.y);
        den += (e0 + e1) + (e2 + e3);
        acc += e0 * from_bf16(g0) + e1 * from_bf16(g1) + e2 * from_bf16(g2) + e3 * from_bf16(g3);
    }
    for (; i < end; i++) {
        int2 rv = sedge[i];
        float ex = __int_as_float(rv.y);
        den += ex;
        acc += ex * from_bf16(h1b[(size_t)rv.x * H + lane]);
    }
    // self loop (src = dst = n, edge_attr = mean)
    {
        float lg = a_s[n] + a_d[n] + scal[0] * scal[1];
        lg = lg > 0.f ? lg : NEG_SLOPE * lg;
        float ex = __expf(lg);
        den += ex;
        acc += ex * from_bf16(h1b[(size_t)n * H + lane]);
    }
    float hr = acc / (den + EPSF) + bias1[lane];
    hr = fmaxf(hr, 0.f);
    // fused gemm2: h2 = hr @ W2  (64 -> 2)
    float p0 = hr * W2[lane * C + 0];
    float p1 = hr * W2[lane * C + 1];
    for (int off = 32; off; off >>= 1) {
        p0 += __shfl_down(p0, off, 64);
        p1 += __shfl_down(p1, off, 64);
    }
    if (lane == 0) {
        h2[(size_t)n * C + 0] = p0;
        h2[(size_t)n * C + 1] = p1;
        a_s2[n] = p0 * att_src2[0] + p1 * att_src2[1];
        a_d2[n] = p0 * att_dst2[0] + p1 * att_dst2[1];
    }
}

// ---------- layer 2 aggregation (wave per dst node, lanes over edges) + log_softmax ----------
__global__ __launch_bounds__(256) void agg2_kernel(
        const int* __restrict__ row, const int2* __restrict__ sedge, const float* __restrict__ sea2,
        const float* __restrict__ scal,
        const float* __restrict__ a_s2, const float* __restrict__ a_d2,
        const float* __restrict__ h2, const float* __restrict__ bias2,
        float* __restrict__ out, int N) {
    int n = (blockIdx.x << 2) + (threadIdx.x >> 6);
    int lane = threadIdx.x & 63;
    if (n >= N) return;
    float c2 = scal[2];
    float ad = a_d2[n];
    int beg = row[n], end = row[n + 1];
    float den = 0.f, m0 = 0.f, m1 = 0.f;
    for (int i = beg + lane; i < end; i += 64) {
        int s = sedge[i].x;
        float lg = a_s2[s] + ad + sea2[i] * c2;
        lg = lg > 0.f ? lg : NEG_SLOPE * lg;
        float ex = __expf(lg);
        den += ex;
        m0 += ex * h2[(size_t)s * C + 0];
        m1 += ex * h2[(size_t)s * C + 1];
    }
    if (lane == 0) {   // self loop
        float lg = a_s2[n] + ad + scal[0] * c2;
        lg = lg > 0.f ? lg : NEG_SLOPE * lg;
        float ex = __expf(lg);
        den += ex;
        m0 += ex * h2[(size_t)n * C + 0];
        m1 += ex * h2[(size_t)n * C + 1];
    }
    for (int off = 32; off; off >>= 1) {
        den += __shfl_down(den, off, 64);
        m0  += __shfl_down(m0, off, 64);
        m1  += __shfl_down(m1, off, 64);
    }
    if (lane == 0) {
        float dn = den + EPSF;
        float o0 = m0 / dn + bias2[0];
        float o1 = m1 / dn + bias2[1];
        float mx = fmaxf(o0, o1);
        float lse = mx + logf(expf(o0 - mx) + expf(o1 - mx));
        out[(size_t)n * C + 0] = o0 - lse;
        out[(size_t)n * C + 1] = o1 - lse;
    }
}

extern "C" void kernel_launch(void* const* d_in, const int* in_sizes, int n_in,
                              void* d_out, int out_size, void* d_ws, size_t ws_size,
                              hipStream_t stream) {
    const float* x        = (const float*)d_in[0];
    const int*   ei       = (const int*)d_in[1];
    const float* ea       = (const float*)d_in[2];
    const float* W1       = (const float*)d_in[3];
    const float* att_src1 = (const float*)d_in[4];
    const float* att_dst1 = (const float*)d_in[5];
    const float* W_edge1  = (const float*)d_in[6];
    const float* att_edge1= (const float*)d_in[7];
    const float* bias1    = (const float*)d_in[8];
    const float* W2       = (const float*)d_in[9];
    const float* att_src2 = (const float*)d_in[10];
    const float* att_dst2 = (const float*)d_in[11];
    const float* W_edge2  = (const float*)d_in[12];
    const float* att_edge2= (const float*)d_in[13];
    const float* bias2    = (const float*)d_in[14];

    const int N  = in_sizes[0] / FIN;
    const int E  = in_sizes[1] / 2;
    const int* srcp = ei;
    const int* dstp = ei + E;
    const int NBUCK = (N + (1 << BSHIFT) - 1) >> BSHIFT;   // 98 for N=100k

    char* wsb = (char*)d_ws;
    size_t off = 0;
    auto alloc = [&](size_t bytes) { void* p = wsb + off; off += (bytes + 255) & ~size_t(255); return p; };
    int*   bcount = (int*)alloc((size_t)NBUCK_MAX * 4);
    float* sum_ea = (float*)alloc(4);
    size_t zbytes = off;                        // bcount + sum_ea must be zeroed
    int*   bbase  = (int*)alloc((size_t)(NBUCK_MAX + 1) * 4);
    int*   bcursor= (int*)alloc((size_t)NBUCK_MAX * 4);
    int*   row    = (int*)alloc((size_t)(N + 1) * 4);
    int2*  sedge  = (int2*)alloc((size_t)E * 8);
    float* sea2   = (float*)alloc((size_t)E * 4);
    int2*  staging= (int2*)alloc((size_t)E * 8);
    u16*   h1b    = (u16*)alloc((size_t)N * H * 2);
    u16*   Wt_hi  = (u16*)alloc((size_t)FIN * H * 2);
    u16*   Wt_lo  = (u16*)alloc((size_t)FIN * H * 2);
    float* a_s1   = (float*)alloc((size_t)N * 4);
    float* a_d1   = (float*)alloc((size_t)N * 4);
    float* h2     = (float*)alloc((size_t)N * C * 4);
    float* a_s2   = (float*)alloc((size_t)N * 4);
    float* a_d2   = (float*)alloc((size_t)N * 4);
    float* scal   = (float*)alloc(3 * 4);

    hipMemsetAsync(d_ws, 0, zbytes, stream);

    ea_sum_kernel<<<1024, 256, 0, stream>>>(ea, E, sum_ea);
    scalars_kernel<<<1, 64, 0, stream>>>(sum_ea, E, W_edge1, att_edge1, W_edge2, att_edge2, scal);
    wprep_kernel<<<(FIN * H + 255) / 256, 256, 0, stream>>>(W1, Wt_hi, Wt_lo);
    bcount_kernel<<<256, 256, 0, stream>>>(dstp, E, bcount, NBUCK);
    bscan_kernel<<<1, 1024, 0, stream>>>(bcount, NBUCK, E, bbase, bcursor, row + N);
    stage_kernel<<<(E + CHUNK - 1) / CHUNK, 256, 0, stream>>>(srcp, dstp, ea, E, bcursor, staging, NBUCK);
    gemm1_mfma_kernel<<<(N + 63) / 64, 256, 0, stream>>>(x, Wt_hi, Wt_lo, att_src1, att_dst1,
                                                         h1b, a_s1, a_d1, N);
    bfin_kernel<<<NBUCK, 256, 0, stream>>>(staging, bbase, scal, a_s1, a_d1, row, sedge, sea2, N);
    agg1_kernel<<<(N + 3) / 4, 256, 0, stream>>>(row, sedge, scal, a_s1, a_d1, h1b,
                                                 bias1, W2, att_src2, att_dst2,
                                                 h2, a_s2, a_d2, N);
    agg2_kernel<<<(N + 3) / 4, 256, 0, stream>>>(row, sedge, sea2, scal, a_s2, a_d2, h2, bias2,
                                                 (float*)d_out, N);
}

// Round 7
// 352.989 us; speedup vs baseline: 1.1520x; 1.1520x over previous
//
#include <hip/hip_runtime.h>
#include <math.h>

#define NEG_SLOPE 0.2f
#define EPSF 1e-16f

constexpr int FIN = 128;
constexpr int H   = 64;
constexpr int C   = 2;
constexpr int BSHIFT = 8;               // nodes per bucket = 256
constexpr int NBUCK_MAX = 1024;         // supports N <= 256k at BSHIFT=8
constexpr int CHUNK = 4096;             // edges per stage block
constexpr int CAP   = 6144;             // max edges per bucket for LDS fast path

typedef short v8s __attribute__((ext_vector_type(8)));
typedef float v4f __attribute__((ext_vector_type(4)));
typedef unsigned short u16;

// round-to-nearest-even fp32 -> bf16 split (hi + lo captures ~17 mantissa bits)
__device__ inline void split_bf16(float v, u16& hi, u16& lo) {
    unsigned u = __float_as_uint(v);
    unsigned r = (u + 0x7FFFu + ((u >> 16) & 1u)) >> 16;
    hi = (u16)r;
    float hf = __uint_as_float(r << 16);
    float l = v - hf;
    unsigned ul = __float_as_uint(l);
    lo = (u16)((ul + 0x7FFFu + ((ul >> 16) & 1u)) >> 16);
}

__device__ inline u16 to_bf16(float v) {
    unsigned u = __float_as_uint(v);
    return (u16)((u + 0x7FFFu + ((u >> 16) & 1u)) >> 16);
}
__device__ inline float from_bf16(u16 h) {
    return __uint_as_float((unsigned)h << 16);
}

// ---------- scalar precompute ----------
__global__ void ea_sum_kernel(const float* __restrict__ ea, int E, float* __restrict__ out) {
    float acc = 0.f;
    for (int i = blockIdx.x * blockDim.x + threadIdx.x; i < E; i += gridDim.x * blockDim.x)
        acc += ea[i];
    for (int off = 32; off; off >>= 1) acc += __shfl_down(acc, off, 64);
    __shared__ float wsum[4];
    int lane = threadIdx.x & 63, wv = threadIdx.x >> 6;
    if (lane == 0) wsum[wv] = acc;
    __syncthreads();
    if (threadIdx.x == 0) atomicAdd(out, wsum[0] + wsum[1] + wsum[2] + wsum[3]);
}

__global__ void scalars_kernel(const float* __restrict__ sum_ea, int E,
                               const float* __restrict__ W_edge1, const float* __restrict__ att_edge1,
                               const float* __restrict__ W_edge2, const float* __restrict__ att_edge2,
                               float* __restrict__ out3) {
    if (threadIdx.x == 0) {
        float m = *sum_ea / (float)E;
        float c1 = 0.f;
        for (int i = 0; i < H; i++) c1 += W_edge1[i] * att_edge1[i];
        float c2 = 0.f;
        for (int i = 0; i < C; i++) c2 += W_edge2[i] * att_edge2[i];
        out3[0] = m; out3[1] = c1; out3[2] = c2;
    }
}

// ---------- W1 prep: transpose to [f][k] + split to bf16 hi/lo ----------
__global__ void wprep_kernel(const float* __restrict__ W1,
                             u16* __restrict__ Wt_hi, u16* __restrict__ Wt_lo) {
    int idx = blockIdx.x * 256 + threadIdx.x;
    if (idx >= FIN * H) return;
    int k = idx >> 6, f = idx & 63;           // W1 is [k][f]
    u16 h, l;
    split_bf16(W1[idx], h, l);
    Wt_hi[f * FIN + k] = h;
    Wt_lo[f * FIN + k] = l;
}

// ---------- P0: bucket counts (LDS-aggregated) ----------
__global__ __launch_bounds__(256) void bcount_kernel(const int* __restrict__ dst, int E,
                                                     int* __restrict__ bcount, int NBUCK) {
    __shared__ int lh[NBUCK_MAX];
    for (int i = threadIdx.x; i < NBUCK_MAX; i += 256) lh[i] = 0;
    __syncthreads();
    for (int e = blockIdx.x * 256 + threadIdx.x; e < E; e += gridDim.x * 256)
        atomicAdd(&lh[dst[e] >> BSHIFT], 1);
    __syncthreads();
    for (int i = threadIdx.x; i < NBUCK; i += 256)
        if (lh[i]) atomicAdd(&bcount[i], lh[i]);
}

// ---------- P1: scan bucket counts -> bbase, bcursor ----------
__global__ __launch_bounds__(1024) void bscan_kernel(const int* __restrict__ bcount, int NBUCK, int E,
                                                     int* __restrict__ bbase, int* __restrict__ bcursor,
                                                     int* __restrict__ rowN) {
    __shared__ int sh[1024];
    int t = threadIdx.x;
    int v = (t < NBUCK) ? bcount[t] : 0;
    sh[t] = v;
    __syncthreads();
    for (int off = 1; off < 1024; off <<= 1) {
        int u = (t >= off) ? sh[t - off] : 0;
        __syncthreads();
        sh[t] += u;
        __syncthreads();
    }
    if (t < NBUCK) { bbase[t] = sh[t] - v; bcursor[t] = sh[t] - v; }
    if (t == 0) { bbase[NBUCK] = E; *rowN = E; }
}

// ---------- P2: stage edges into bucket-major order (coalesced runs) ----------
__global__ __launch_bounds__(256) void stage_kernel(
        const int* __restrict__ src, const int* __restrict__ dst, const float* __restrict__ ea,
        int E, int* __restrict__ bcursor, int2* __restrict__ staging, int NBUCK) {
    __shared__ int   cur[NBUCK_MAX];
    __shared__ int   gofs[NBUCK_MAX];
    __shared__ int2  sbuf[CHUNK];
    __shared__ short sbkt[CHUNK];
    __shared__ int   red[256];
    int t = threadIdx.x;
    int base = blockIdx.x * CHUNK;
    int cnt = min(CHUNK, E - base);
    for (int i = t; i < NBUCK_MAX; i += 256) cur[i] = 0;
    __syncthreads();
    for (int i = t; i < cnt; i += 256)
        atomicAdd(&cur[dst[base + i] >> BSHIFT], 1);
    __syncthreads();
    int i0 = t * 4;
    int v0 = cur[i0], v1 = cur[i0 + 1], v2 = cur[i0 + 2], v3 = cur[i0 + 3];
    int s = v0 + v1 + v2 + v3;
    red[t] = s;
    __syncthreads();
    for (int off = 1; off < 256; off <<= 1) {
        int u = (t >= off) ? red[t - off] : 0;
        __syncthreads();
        red[t] += u;
        __syncthreads();
    }
    int run = red[t] - s;
    __syncthreads();
    int p = run;
    if (v0) gofs[i0]     = atomicAdd(&bcursor[i0],     v0) - p;
    cur[i0] = p; p += v0;
    if (v1) gofs[i0 + 1] = atomicAdd(&bcursor[i0 + 1], v1) - p;
    cur[i0 + 1] = p; p += v1;
    if (v2) gofs[i0 + 2] = atomicAdd(&bcursor[i0 + 2], v2) - p;
    cur[i0 + 2] = p; p += v2;
    if (v3) gofs[i0 + 3] = atomicAdd(&bcursor[i0 + 3], v3) - p;
    cur[i0 + 3] = p; p += v3;
    __syncthreads();
    for (int i = t; i < cnt; i += 256) {
        int e = base + i;
        int d = dst[e];
        int b = d >> BSHIFT;
        int slot = atomicAdd(&cur[b], 1);
        sbuf[slot] = make_int2(src[e] | ((d & ((1 << BSHIFT) - 1)) << 20), __float_as_int(ea[e]));
        sbkt[slot] = (short)b;
    }
    __syncthreads();
    for (int j = t; j < cnt; j += 256)
        staging[gofs[sbkt[j]] + j] = sbuf[j];
}

// ---------- layer 1 GEMM via split-bf16 MFMA; h1 stored as bf16 ----------
__global__ __launch_bounds__(256) void gemm1_mfma_kernel(
        const float* __restrict__ x,
        const u16* __restrict__ Wt_hi, const u16* __restrict__ Wt_lo,
        const float* __restrict__ att_src, const float* __restrict__ att_dst,
        u16* __restrict__ h1b, float* __restrict__ a_s, float* __restrict__ a_d, int N) {
    int w = threadIdx.x >> 6, lane = threadIdx.x & 63;
    int m = lane & 15, q = lane >> 4;
    int base = blockIdx.x * 64 + w * 16;
    int nodeA = base + m;
    bool inA = nodeA < N;
    const float* xrow = x + (size_t)nodeA * FIN;

    v8s ah[4], al[4];
    #pragma unroll
    for (int kt = 0; kt < 4; kt++) {
        float xv[8];
        if (inA) {
            const float4* p = (const float4*)(xrow + kt * 32 + q * 8);
            float4 u0 = p[0], u1 = p[1];
            xv[0] = u0.x; xv[1] = u0.y; xv[2] = u0.z; xv[3] = u0.w;
            xv[4] = u1.x; xv[5] = u1.y; xv[6] = u1.z; xv[7] = u1.w;
        } else {
            #pragma unroll
            for (int j = 0; j < 8; j++) xv[j] = 0.f;
        }
        #pragma unroll
        for (int j = 0; j < 8; j++) {
            u16 hb, lb;
            split_bf16(xv[j], hb, lb);
            ah[kt][j] = (short)hb;
            al[kt][j] = (short)lb;
        }
    }

    float ps[4] = {0.f, 0.f, 0.f, 0.f};
    float pd[4] = {0.f, 0.f, 0.f, 0.f};
    #pragma unroll
    for (int ft = 0; ft < 4; ft++) {
        v4f acc = {0.f, 0.f, 0.f, 0.f};
        const u16* bh_base = Wt_hi + (ft * 16 + m) * FIN + q * 8;
        const u16* bl_base = Wt_lo + (ft * 16 + m) * FIN + q * 8;
        #pragma unroll
        for (int kt = 0; kt < 4; kt++) {
            v8s bh = *(const v8s*)(bh_base + kt * 32);
            v8s bl = *(const v8s*)(bl_base + kt * 32);
            acc = __builtin_amdgcn_mfma_f32_16x16x32_bf16(ah[kt], bh, acc, 0, 0, 0);
            acc = __builtin_amdgcn_mfma_f32_16x16x32_bf16(al[kt], bh, acc, 0, 0, 0);
            acc = __builtin_amdgcn_mfma_f32_16x16x32_bf16(ah[kt], bl, acc, 0, 0, 0);
        }
        int f = ft * 16 + m;               // C col
        float asf = att_src[f], adf = att_dst[f];
        #pragma unroll
        for (int r = 0; r < 4; r++) {      // C row = q*4 + r
            int node = base + q * 4 + r;
            if (node < N) h1b[(size_t)node * H + f] = to_bf16(acc[r]);
            ps[r] += acc[r] * asf;
            pd[r] += acc[r] * adf;
        }
    }
    #pragma unroll
    for (int msk = 1; msk < 16; msk <<= 1) {
        #pragma unroll
        for (int r = 0; r < 4; r++) {
            ps[r] += __shfl_xor(ps[r], msk, 64);
            pd[r] += __shfl_xor(pd[r], msk, 64);
        }
    }
    if (m == 0) {
        #pragma unroll
        for (int r = 0; r < 4; r++) {
            int node = base + q * 4 + r;
            if (node < N) { a_s[node] = ps[r]; a_d[node] = pd[r]; }
        }
    }
}

// ---------- P3: per-bucket finalize: CSR rows + LDS-buffered sort + ex1 precompute ----------
__global__ __launch_bounds__(256) void bfin_kernel(
        const int2* __restrict__ staging, const int* __restrict__ bbase,
        const float* __restrict__ scal,
        const float* __restrict__ a_s1, const float* __restrict__ a_d1,
        int* __restrict__ row, int2* __restrict__ sedge, float* __restrict__ sea2, int N) {
    __shared__ int   nh[256];
    __shared__ int   red[256];
    __shared__ int2  ebuf[CAP];    // 48 KB
    __shared__ float abuf[CAP];    // 24 KB
    int b = blockIdx.x, t = threadIdx.x;
    int beg = bbase[b], end = bbase[b + 1];
    int cnt = end - beg;
    int node0 = b << BSHIFT;
    float c1 = scal[1];
    nh[t] = 0;
    __syncthreads();
    for (int i = beg + t; i < end; i += 256)
        atomicAdd(&nh[(unsigned)staging[i].x >> 20], 1);
    __syncthreads();
    int v = nh[t];
    red[t] = v;
    __syncthreads();
    for (int off = 1; off < 256; off <<= 1) {
        int u = (t >= off) ? red[t - off] : 0;
        __syncthreads();
        red[t] += u;
        __syncthreads();
    }
    int excl = red[t] - v;                 // exclusive prefix within bucket
    int node = node0 + t;
    if (node < N) row[node] = beg + excl;
    __syncthreads();
    bool fast = (cnt <= CAP);
    nh[t] = fast ? excl : beg + excl;      // relative (LDS) or absolute (fallback) cursor
    __syncthreads();
    for (int i = beg + t; i < end; i += 256) {
        int2 r = staging[i];
        int dlow = (unsigned)r.x >> 20;
        int sn = r.x & 0xFFFFF;
        float eav = __int_as_float(r.y);
        float lg = a_s1[sn] + a_d1[node0 + dlow] + eav * c1;
        lg = lg > 0.f ? lg : NEG_SLOPE * lg;
        float ex = __expf(lg);
        int pos = atomicAdd(&nh[dlow], 1);
        if (fast) {
            ebuf[pos] = make_int2(sn, __float_as_int(ex));
            abuf[pos] = eav;
        } else {
            sedge[pos] = make_int2(sn, __float_as_int(ex));
            sea2[pos] = eav;
        }
    }
    __syncthreads();
    if (fast) {
        for (int j = t; j < cnt; j += 256) {
            sedge[beg + j] = ebuf[j];
            sea2[beg + j]  = abuf[j];
        }
    }
}

// ---------- layer 1 aggregation (wave per dst node; ex precomputed) + gemm2 fused ----------
__global__ __launch_bounds__(256) void agg1_kernel(
        const int* __restrict__ row, const int2* __restrict__ sedge,
        const float* __restrict__ scal,
        const float* __restrict__ a_s, const float* __restrict__ a_d,
        const u16* __restrict__ h1b,
        const float* __restrict__ bias1, const float* __restrict__ W2,
        const float* __restrict__ att_src2, const float* __restrict__ att_dst2,
        float* __restrict__ h2, float* __restrict__ a_s2, float* __restrict__ a_d2,
        int N) {
    int n = (blockIdx.x << 2) + (threadIdx.x >> 6);   // dst node
    int lane = threadIdx.x & 63;
    if (n >= N) return;
    int beg = row[n], end = row[n + 1];
    float den = 0.f, acc = 0.f;
    int i = beg;
    for (; i + 4 <= end; i += 4) {
        int2 r0 = sedge[i], r1 = sedge[i + 1], r2 = sedge[i + 2], r3 = sedge[i + 3];
        u16 g0 = h1b[(size_t)r0.x * H + lane];
        u16 g1 = h1b[(size_t)r1.x * H + lane];
        u16 g2 = h1b[(size_t)r2.x * H + lane];
        u16 g3 = h1b[(size_t)r3.x * H + lane];
        float e0 = __int_as_float(r0.y), e1 = __int_as_float(r1.y);
        float e2 = __int_as_float(r2.y), e3 = __int_as_float(r3.y);
        den += (e0 + e1) + (e2 + e3);
        acc += e0 * from_bf16(g0) + e1 * from_bf16(g1) + e2 * from_bf16(g2) + e3 * from_bf16(g3);
    }
    for (; i < end; i++) {
        int2 rv = sedge[i];
        float ex = __int_as_float(rv.y);
        den += ex;
        acc += ex * from_bf16(h1b[(size_t)rv.x * H + lane]);
    }
    // self loop (src = dst = n, edge_attr = mean)
    {
        float lg = a_s[n] + a_d[n] + scal[0] * scal[1];
        lg = lg > 0.f ? lg : NEG_SLOPE * lg;
        float ex = __expf(lg);
        den += ex;
        acc += ex * from_bf16(h1b[(size_t)n * H + lane]);
    }
    float hr = acc / (den + EPSF) + bias1[lane];
    hr = fmaxf(hr, 0.f);
    // fused gemm2: h2 = hr @ W2  (64 -> 2)
    float p0 = hr * W2[lane * C + 0];
    float p1 = hr * W2[lane * C + 1];
    for (int off = 32; off; off >>= 1) {
        p0 += __shfl_down(p0, off, 64);
        p1 += __shfl_down(p1, off, 64);
    }
    if (lane == 0) {
        h2[(size_t)n * C + 0] = p0;
        h2[(size_t)n * C + 1] = p1;
        a_s2[n] = p0 * att_src2[0] + p1 * att_src2[1];
        a_d2[n] = p0 * att_dst2[0] + p1 * att_dst2[1];
    }
}

// ---------- layer 2 aggregation (wave per dst node, lanes over edges) + log_softmax ----------
__global__ __launch_bounds__(256) void agg2_kernel(
        const int* __restrict__ row, const int2* __restrict__ sedge, const float* __restrict__ sea2,
        const float* __restrict__ scal,
        const float* __restrict__ a_s2, const float* __restrict__ a_d2,
        const float* __restrict__ h2, const float* __restrict__ bias2,
        float* __restrict__ out, int N) {
    int n = (blockIdx.x << 2) + (threadIdx.x >> 6);
    int lane = threadIdx.x & 63;
    if (n >= N) return;
    float c2 = scal[2];
    float ad = a_d2[n];
    int beg = row[n], end = row[n + 1];
    float den = 0.f, m0 = 0.f, m1 = 0.f;
    for (int i = beg + lane; i < end; i += 64) {
        int s = sedge[i].x;
        float lg = a_s2[s] + ad + sea2[i] * c2;
        lg = lg > 0.f ? lg : NEG_SLOPE * lg;
        float ex = __expf(lg);
        den += ex;
        m0 += ex * h2[(size_t)s * C + 0];
        m1 += ex * h2[(size_t)s * C + 1];
    }
    if (lane == 0) {   // self loop
        float lg = a_s2[n] + ad + scal[0] * c2;
        lg = lg > 0.f ? lg : NEG_SLOPE * lg;
        float ex = __expf(lg);
        den += ex;
        m0 += ex * h2[(size_t)n * C + 0];
        m1 += ex * h2[(size_t)n * C + 1];
    }
    for (int off = 32; off; off >>= 1) {
        den += __shfl_down(den, off, 64);
        m0  += __shfl_down(m0, off, 64);
        m1  += __shfl_down(m1, off, 64);
    }
    if (lane == 0) {
        float dn = den + EPSF;
        float o0 = m0 / dn + bias2[0];
        float o1 = m1 / dn + bias2[1];
        float mx = fmaxf(o0, o1);
        float lse = mx + logf(expf(o0 - mx) + expf(o1 - mx));
        out[(size_t)n * C + 0] = o0 - lse;
        out[(size_t)n * C + 1] = o1 - lse;
    }
}

extern "C" void kernel_launch(void* const* d_in, const int* in_sizes, int n_in,
                              void* d_out, int out_size, void* d_ws, size_t ws_size,
                              hipStream_t stream) {
    const float* x        = (const float*)d_in[0];
    const int*   ei       = (const int*)d_in[1];
    const float* ea       = (const float*)d_in[2];
    const float* W1       = (const float*)d_in[3];
    const float* att_src1 = (const float*)d_in[4];
    const float* att_dst1 = (const float*)d_in[5];
    const float* W_edge1  = (const float*)d_in[6];
    const float* att_edge1= (const float*)d_in[7];
    const float* bias1    = (const float*)d_in[8];
    const float* W2       = (const float*)d_in[9];
    const float* att_src2 = (const float*)d_in[10];
    const float* att_dst2 = (const float*)d_in[11];
    const float* W_edge2  = (const float*)d_in[12];
    const float* att_edge2= (const float*)d_in[13];
    const float* bias2    = (const float*)d_in[14];

    const int N  = in_sizes[0] / FIN;
    const int E  = in_sizes[1] / 2;
    const int* srcp = ei;
    const int* dstp = ei + E;
    const int NBUCK = (N + (1 << BSHIFT) - 1) >> BSHIFT;   // 391 for N=100k

    char* wsb = (char*)d_ws;
    size_t off = 0;
    auto alloc = [&](size_t bytes) { void* p = wsb + off; off += (bytes + 255) & ~size_t(255); return p; };
    int*   bcount = (int*)alloc((size_t)NBUCK_MAX * 4);
    float* sum_ea = (float*)alloc(4);
    size_t zbytes = off;                        // bcount + sum_ea must be zeroed
    int*   bbase  = (int*)alloc((size_t)(NBUCK_MAX + 1) * 4);
    int*   bcursor= (int*)alloc((size_t)NBUCK_MAX * 4);
    int*   row    = (int*)alloc((size_t)(N + 1) * 4);
    int2*  sedge  = (int2*)alloc((size_t)E * 8);
    float* sea2   = (float*)alloc((size_t)E * 4);
    int2*  staging= (int2*)alloc((size_t)E * 8);
    u16*   h1b    = (u16*)alloc((size_t)N * H * 2);
    u16*   Wt_hi  = (u16*)alloc((size_t)FIN * H * 2);
    u16*   Wt_lo  = (u16*)alloc((size_t)FIN * H * 2);
    float* a_s1   = (float*)alloc((size_t)N * 4);
    float* a_d1   = (float*)alloc((size_t)N * 4);
    float* h2     = (float*)alloc((size_t)N * C * 4);
    float* a_s2   = (float*)alloc((size_t)N * 4);
    float* a_d2   = (float*)alloc((size_t)N * 4);
    float* scal   = (float*)alloc(3 * 4);

    hipMemsetAsync(d_ws, 0, zbytes, stream);

    ea_sum_kernel<<<1024, 256, 0, stream>>>(ea, E, sum_ea);
    scalars_kernel<<<1, 64, 0, stream>>>(sum_ea, E, W_edge1, att_edge1, W_edge2, att_edge2, scal);
    wprep_kernel<<<(FIN * H + 255) / 256, 256, 0, stream>>>(W1, Wt_hi, Wt_lo);
    bcount_kernel<<<256, 256, 0, stream>>>(dstp, E, bcount, NBUCK);
    bscan_kernel<<<1, 1024, 0, stream>>>(bcount, NBUCK, E, bbase, bcursor, row + N);
    stage_kernel<<<(E + CHUNK - 1) / CHUNK, 256, 0, stream>>>(srcp, dstp, ea, E, bcursor, staging, NBUCK);
    gemm1_mfma_kernel<<<(N + 63) / 64, 256, 0, stream>>>(x, Wt_hi, Wt_lo, att_src1, att_dst1,
                                                         h1b, a_s1, a_d1, N);
    bfin_kernel<<<NBUCK, 256, 0, stream>>>(staging, bbase, scal, a_s1, a_d1, row, sedge, sea2, N);
    agg1_kernel<<<(N + 3) / 4, 256, 0, stream>>>(row, sedge, scal, a_s1, a_d1, h1b,
                                                 bias1, W2, att_src2, att_dst2,
                                                 h2, a_s2, a_d2, N);
    agg2_kernel<<<(N + 3) / 4, 256, 0, stream>>>(row, sedge, sea2, scal, a_s2, a_d2, h2, bias2,
                                                 (float*)d_out, N);
}

// Round 8
// 323.886 us; speedup vs baseline: 1.2555x; 1.0899x over previous
//
#include <hip/hip_runtime.h>
#include <math.h>

#define NEG_SLOPE 0.2f
#define EPSF 1e-16f

constexpr int FIN = 128;
constexpr int H   = 64;
constexpr int C   = 2;
constexpr int BSHIFT = 8;               // nodes per bucket = 256
constexpr int NBUCK_MAX = 1024;         // supports N <= 256k at BSHIFT=8
constexpr int CHUNK = 4096;             // edges per stage block
constexpr int CAP   = 6144;             // max edges per bucket for LDS fast path

typedef short v8s __attribute__((ext_vector_type(8)));
typedef float v4f __attribute__((ext_vector_type(4)));
typedef unsigned short u16;

// round-to-nearest-even fp32 -> bf16 split (hi + lo captures ~17 mantissa bits)
__device__ inline void split_bf16(float v, u16& hi, u16& lo) {
    unsigned u = __float_as_uint(v);
    unsigned r = (u + 0x7FFFu + ((u >> 16) & 1u)) >> 16;
    hi = (u16)r;
    float hf = __uint_as_float(r << 16);
    float l = v - hf;
    unsigned ul = __float_as_uint(l);
    lo = (u16)((ul + 0x7FFFu + ((ul >> 16) & 1u)) >> 16);
}

__device__ inline u16 to_bf16(float v) {
    unsigned u = __float_as_uint(v);
    return (u16)((u + 0x7FFFu + ((u >> 16) & 1u)) >> 16);
}
__device__ inline float from_bf16(u16 h) {
    return __uint_as_float((unsigned)h << 16);
}

// ---------- fused: ea sum + bucket counts ----------
__global__ __launch_bounds__(256) void pre_kernel(const float* __restrict__ ea,
                                                  const int* __restrict__ dst, int E,
                                                  float* __restrict__ out, int* __restrict__ bcount,
                                                  int NBUCK) {
    __shared__ int lh[NBUCK_MAX];
    for (int i = threadIdx.x; i < NBUCK_MAX; i += 256) lh[i] = 0;
    __syncthreads();
    float acc = 0.f;
    for (int e = blockIdx.x * 256 + threadIdx.x; e < E; e += gridDim.x * 256) {
        acc += ea[e];
        atomicAdd(&lh[dst[e] >> BSHIFT], 1);
    }
    for (int off = 32; off; off >>= 1) acc += __shfl_down(acc, off, 64);
    __shared__ float wsum[4];
    int lane = threadIdx.x & 63, wv = threadIdx.x >> 6;
    if (lane == 0) wsum[wv] = acc;
    __syncthreads();
    if (threadIdx.x == 0) atomicAdd(out, wsum[0] + wsum[1] + wsum[2] + wsum[3]);
    for (int i = threadIdx.x; i < NBUCK; i += 256)
        if (lh[i]) atomicAdd(&bcount[i], lh[i]);
}

__global__ void scalars_kernel(const float* __restrict__ sum_ea, int E,
                               const float* __restrict__ W_edge1, const float* __restrict__ att_edge1,
                               const float* __restrict__ W_edge2, const float* __restrict__ att_edge2,
                               float* __restrict__ out3) {
    if (threadIdx.x == 0) {
        float m = *sum_ea / (float)E;
        float c1 = 0.f;
        for (int i = 0; i < H; i++) c1 += W_edge1[i] * att_edge1[i];
        float c2 = 0.f;
        for (int i = 0; i < C; i++) c2 += W_edge2[i] * att_edge2[i];
        out3[0] = m; out3[1] = c1; out3[2] = c2;
    }
}

// ---------- W1 prep: transpose to [f][k] + split to bf16 hi/lo ----------
__global__ void wprep_kernel(const float* __restrict__ W1,
                             u16* __restrict__ Wt_hi, u16* __restrict__ Wt_lo) {
    int idx = blockIdx.x * 256 + threadIdx.x;
    if (idx >= FIN * H) return;
    int k = idx >> 6, f = idx & 63;           // W1 is [k][f]
    u16 h, l;
    split_bf16(W1[idx], h, l);
    Wt_hi[f * FIN + k] = h;
    Wt_lo[f * FIN + k] = l;
}

// ---------- P1: scan bucket counts -> bbase, bcursor ----------
__global__ __launch_bounds__(1024) void bscan_kernel(const int* __restrict__ bcount, int NBUCK, int E,
                                                     int* __restrict__ bbase, int* __restrict__ bcursor,
                                                     int* __restrict__ rowN) {
    __shared__ int sh[1024];
    int t = threadIdx.x;
    int v = (t < NBUCK) ? bcount[t] : 0;
    sh[t] = v;
    __syncthreads();
    for (int off = 1; off < 1024; off <<= 1) {
        int u = (t >= off) ? sh[t - off] : 0;
        __syncthreads();
        sh[t] += u;
        __syncthreads();
    }
    if (t < NBUCK) { bbase[t] = sh[t] - v; bcursor[t] = sh[t] - v; }
    if (t == 0) { bbase[NBUCK] = E; *rowN = E; }
}

// ---------- P2: stage edges into bucket-major order (coalesced runs) ----------
__global__ __launch_bounds__(256) void stage_kernel(
        const int* __restrict__ src, const int* __restrict__ dst, const float* __restrict__ ea,
        int E, int* __restrict__ bcursor, int2* __restrict__ staging, int NBUCK) {
    __shared__ int   cur[NBUCK_MAX];
    __shared__ int   gofs[NBUCK_MAX];
    __shared__ int2  sbuf[CHUNK];
    __shared__ short sbkt[CHUNK];
    __shared__ int   red[256];
    int t = threadIdx.x;
    int base = blockIdx.x * CHUNK;
    int cnt = min(CHUNK, E - base);
    for (int i = t; i < NBUCK_MAX; i += 256) cur[i] = 0;
    __syncthreads();
    for (int i = t; i < cnt; i += 256)
        atomicAdd(&cur[dst[base + i] >> BSHIFT], 1);
    __syncthreads();
    int i0 = t * 4;
    int v0 = cur[i0], v1 = cur[i0 + 1], v2 = cur[i0 + 2], v3 = cur[i0 + 3];
    int s = v0 + v1 + v2 + v3;
    red[t] = s;
    __syncthreads();
    for (int off = 1; off < 256; off <<= 1) {
        int u = (t >= off) ? red[t - off] : 0;
        __syncthreads();
        red[t] += u;
        __syncthreads();
    }
    int run = red[t] - s;
    __syncthreads();
    int p = run;
    if (v0) gofs[i0]     = atomicAdd(&bcursor[i0],     v0) - p;
    cur[i0] = p; p += v0;
    if (v1) gofs[i0 + 1] = atomicAdd(&bcursor[i0 + 1], v1) - p;
    cur[i0 + 1] = p; p += v1;
    if (v2) gofs[i0 + 2] = atomicAdd(&bcursor[i0 + 2], v2) - p;
    cur[i0 + 2] = p; p += v2;
    if (v3) gofs[i0 + 3] = atomicAdd(&bcursor[i0 + 3], v3) - p;
    cur[i0 + 3] = p; p += v3;
    __syncthreads();
    for (int i = t; i < cnt; i += 256) {
        int e = base + i;
        int d = dst[e];
        int b = d >> BSHIFT;
        int slot = atomicAdd(&cur[b], 1);
        sbuf[slot] = make_int2(src[e] | ((d & ((1 << BSHIFT) - 1)) << 20), __float_as_int(ea[e]));
        sbkt[slot] = (short)b;
    }
    __syncthreads();
    for (int j = t; j < cnt; j += 256)
        staging[gofs[sbkt[j]] + j] = sbuf[j];
}

// ---------- layer 1 GEMM via split-bf16 MFMA; h1 stored as bf16 ----------
__global__ __launch_bounds__(256) void gemm1_mfma_kernel(
        const float* __restrict__ x,
        const u16* __restrict__ Wt_hi, const u16* __restrict__ Wt_lo,
        const float* __restrict__ att_src, const float* __restrict__ att_dst,
        u16* __restrict__ h1b, float* __restrict__ a_s, float* __restrict__ a_d, int N) {
    int w = threadIdx.x >> 6, lane = threadIdx.x & 63;
    int m = lane & 15, q = lane >> 4;
    int base = blockIdx.x * 64 + w * 16;
    int nodeA = base + m;
    bool inA = nodeA < N;
    const float* xrow = x + (size_t)nodeA * FIN;

    v8s ah[4], al[4];
    #pragma unroll
    for (int kt = 0; kt < 4; kt++) {
        float xv[8];
        if (inA) {
            const float4* p = (const float4*)(xrow + kt * 32 + q * 8);
            float4 u0 = p[0], u1 = p[1];
            xv[0] = u0.x; xv[1] = u0.y; xv[2] = u0.z; xv[3] = u0.w;
            xv[4] = u1.x; xv[5] = u1.y; xv[6] = u1.z; xv[7] = u1.w;
        } else {
            #pragma unroll
            for (int j = 0; j < 8; j++) xv[j] = 0.f;
        }
        #pragma unroll
        for (int j = 0; j < 8; j++) {
            u16 hb, lb;
            split_bf16(xv[j], hb, lb);
            ah[kt][j] = (short)hb;
            al[kt][j] = (short)lb;
        }
    }

    float ps[4] = {0.f, 0.f, 0.f, 0.f};
    float pd[4] = {0.f, 0.f, 0.f, 0.f};
    #pragma unroll
    for (int ft = 0; ft < 4; ft++) {
        v4f acc = {0.f, 0.f, 0.f, 0.f};
        const u16* bh_base = Wt_hi + (ft * 16 + m) * FIN + q * 8;
        const u16* bl_base = Wt_lo + (ft * 16 + m) * FIN + q * 8;
        #pragma unroll
        for (int kt = 0; kt < 4; kt++) {
            v8s bh = *(const v8s*)(bh_base + kt * 32);
            v8s bl = *(const v8s*)(bl_base + kt * 32);
            acc = __builtin_amdgcn_mfma_f32_16x16x32_bf16(ah[kt], bh, acc, 0, 0, 0);
            acc = __builtin_amdgcn_mfma_f32_16x16x32_bf16(al[kt], bh, acc, 0, 0, 0);
            acc = __builtin_amdgcn_mfma_f32_16x16x32_bf16(ah[kt], bl, acc, 0, 0, 0);
        }
        int f = ft * 16 + m;               // C col
        float asf = att_src[f], adf = att_dst[f];
        #pragma unroll
        for (int r = 0; r < 4; r++) {      // C row = q*4 + r
            int node = base + q * 4 + r;
            if (node < N) h1b[(size_t)node * H + f] = to_bf16(acc[r]);
            ps[r] += acc[r] * asf;
            pd[r] += acc[r] * adf;
        }
    }
    #pragma unroll
    for (int msk = 1; msk < 16; msk <<= 1) {
        #pragma unroll
        for (int r = 0; r < 4; r++) {
            ps[r] += __shfl_xor(ps[r], msk, 64);
            pd[r] += __shfl_xor(pd[r], msk, 64);
        }
    }
    if (m == 0) {
        #pragma unroll
        for (int r = 0; r < 4; r++) {
            int node = base + q * 4 + r;
            if (node < N) { a_s[node] = ps[r]; a_d[node] = pd[r]; }
        }
    }
}

// ---------- P3: per-bucket finalize: CSR rows + LDS-buffered sort + ex1 precompute ----------
__global__ __launch_bounds__(256) void bfin_kernel(
        const int2* __restrict__ staging, const int* __restrict__ bbase,
        const float* __restrict__ scal,
        const float* __restrict__ a_s1, const float* __restrict__ a_d1,
        int* __restrict__ row, int2* __restrict__ sedge, float* __restrict__ sea2, int N) {
    __shared__ int   nh[256];
    __shared__ int   red[256];
    __shared__ int2  ebuf[CAP];    // 48 KB
    __shared__ float abuf[CAP];    // 24 KB
    int b = blockIdx.x, t = threadIdx.x;
    int beg = bbase[b], end = bbase[b + 1];
    int cnt = end - beg;
    int node0 = b << BSHIFT;
    float c1 = scal[1];
    nh[t] = 0;
    __syncthreads();
    for (int i = beg + t; i < end; i += 256)
        atomicAdd(&nh[(unsigned)staging[i].x >> 20], 1);
    __syncthreads();
    int v = nh[t];
    red[t] = v;
    __syncthreads();
    for (int off = 1; off < 256; off <<= 1) {
        int u = (t >= off) ? red[t - off] : 0;
        __syncthreads();
        red[t] += u;
        __syncthreads();
    }
    int excl = red[t] - v;                 // exclusive prefix within bucket
    int node = node0 + t;
    if (node < N) row[node] = beg + excl;
    __syncthreads();
    bool fast = (cnt <= CAP);
    nh[t] = fast ? excl : beg + excl;      // relative (LDS) or absolute (fallback) cursor
    __syncthreads();
    for (int i = beg + t; i < end; i += 256) {
        int2 r = staging[i];
        int dlow = (unsigned)r.x >> 20;
        int sn = r.x & 0xFFFFF;
        float eav = __int_as_float(r.y);
        float lg = a_s1[sn] + a_d1[node0 + dlow] + eav * c1;
        lg = lg > 0.f ? lg : NEG_SLOPE * lg;
        float ex = __expf(lg);
        int pos = atomicAdd(&nh[dlow], 1);
        if (fast) {
            ebuf[pos] = make_int2(sn, __float_as_int(ex));
            abuf[pos] = eav;
        } else {
            sedge[pos] = make_int2(sn, __float_as_int(ex));
            sea2[pos] = eav;
        }
    }
    __syncthreads();
    if (fast) {
        for (int j = t; j < cnt; j += 256) {
            sedge[beg + j] = ebuf[j];
            sea2[beg + j]  = abuf[j];
        }
    }
}

// ---------- layer 1 aggregation: 8 groups x 8 lanes; 16B gathers + gemm2 fused ----------
__global__ __launch_bounds__(256) void agg1_kernel(
        const int* __restrict__ row, const int2* __restrict__ sedge,
        const float* __restrict__ scal,
        const float* __restrict__ a_s, const float* __restrict__ a_d,
        const u16* __restrict__ h1b,
        const float* __restrict__ bias1, const float* __restrict__ W2,
        const float* __restrict__ att_src2, const float* __restrict__ att_dst2,
        float* __restrict__ h2, float* __restrict__ a_s2, float* __restrict__ a_d2,
        int N) {
    int n = (blockIdx.x << 2) + (threadIdx.x >> 6);   // dst node
    int lane = threadIdx.x & 63;
    if (n >= N) return;
    int g  = lane >> 3;        // edge slot within an iteration (0..7)
    int fl = lane & 7;         // feature block: features fl*8 .. fl*8+7
    int beg = row[n], end = row[n + 1];
    float den = 0.f;
    float acc[8] = {0.f, 0.f, 0.f, 0.f, 0.f, 0.f, 0.f, 0.f};
    for (int i = beg; i < end; i += 8) {
        int idx = i + g;
        bool valid = idx < end;
        int2 ev = sedge[valid ? idx : beg];
        float ex = valid ? __int_as_float(ev.y) : 0.f;
        const int4* hp = (const int4*)(h1b + (size_t)ev.x * H + fl * 8);
        int4 hv = *hp;
        den += ex;
        acc[0] += ex * __uint_as_float((unsigned)hv.x << 16);
        acc[1] += ex * __uint_as_float((unsigned)hv.x & 0xFFFF0000u);
        acc[2] += ex * __uint_as_float((unsigned)hv.y << 16);
        acc[3] += ex * __uint_as_float((unsigned)hv.y & 0xFFFF0000u);
        acc[4] += ex * __uint_as_float((unsigned)hv.z << 16);
        acc[5] += ex * __uint_as_float((unsigned)hv.z & 0xFFFF0000u);
        acc[6] += ex * __uint_as_float((unsigned)hv.w << 16);
        acc[7] += ex * __uint_as_float((unsigned)hv.w & 0xFFFF0000u);
    }
    // self loop (src = dst = n): group 0 only
    {
        float lg = a_s[n] + a_d[n] + scal[0] * scal[1];
        lg = lg > 0.f ? lg : NEG_SLOPE * lg;
        float ex = __expf(lg);
        if (g == 0) {
            const int4* hp = (const int4*)(h1b + (size_t)n * H + fl * 8);
            int4 hv = *hp;
            den += ex;
            acc[0] += ex * __uint_as_float((unsigned)hv.x << 16);
            acc[1] += ex * __uint_as_float((unsigned)hv.x & 0xFFFF0000u);
            acc[2] += ex * __uint_as_float((unsigned)hv.y << 16);
            acc[3] += ex * __uint_as_float((unsigned)hv.y & 0xFFFF0000u);
            acc[4] += ex * __uint_as_float((unsigned)hv.z << 16);
            acc[5] += ex * __uint_as_float((unsigned)hv.z & 0xFFFF0000u);
            acc[6] += ex * __uint_as_float((unsigned)hv.w << 16);
            acc[7] += ex * __uint_as_float((unsigned)hv.w & 0xFFFF0000u);
        }
    }
    // merge the 8 edge-groups (lanes differing in bits 3,4,5)
    #pragma unroll
    for (int msk = 8; msk < 64; msk <<= 1) {
        den += __shfl_xor(den, msk, 64);
        #pragma unroll
        for (int k = 0; k < 8; k++) acc[k] += __shfl_xor(acc[k], msk, 64);
    }
    // epilogue: divide, bias, relu, fused gemm2 over this lane's 8 features
    float inv = 1.f / (den + EPSF);
    float p0 = 0.f, p1 = 0.f;
    #pragma unroll
    for (int k = 0; k < 8; k++) {
        int f = fl * 8 + k;
        float hr = acc[k] * inv + bias1[f];
        hr = fmaxf(hr, 0.f);
        p0 += hr * W2[f * C + 0];
        p1 += hr * W2[f * C + 1];
    }
    // reduce over the 8 feature blocks (lanes differing in bits 0,1,2)
    #pragma unroll
    for (int msk = 1; msk < 8; msk <<= 1) {
        p0 += __shfl_xor(p0, msk, 64);
        p1 += __shfl_xor(p1, msk, 64);
    }
    if (lane == 0) {
        h2[(size_t)n * C + 0] = p0;
        h2[(size_t)n * C + 1] = p1;
        a_s2[n] = p0 * att_src2[0] + p1 * att_src2[1];
        a_d2[n] = p0 * att_dst2[0] + p1 * att_dst2[1];
    }
}

// ---------- layer 2 aggregation (wave per dst node, lanes over edges) + log_softmax ----------
__global__ __launch_bounds__(256) void agg2_kernel(
        const int* __restrict__ row, const int2* __restrict__ sedge, const float* __restrict__ sea2,
        const float* __restrict__ scal,
        const float* __restrict__ a_s2, const float* __restrict__ a_d2,
        const float* __restrict__ h2, const float* __restrict__ bias2,
        float* __restrict__ out, int N) {
    int n = (blockIdx.x << 2) + (threadIdx.x >> 6);
    int lane = threadIdx.x & 63;
    if (n >= N) return;
    float c2 = scal[2];
    float ad = a_d2[n];
    int beg = row[n], end = row[n + 1];
    float den = 0.f, m0 = 0.f, m1 = 0.f;
    for (int i = beg + lane; i < end; i += 64) {
        int s = sedge[i].x;
        float lg = a_s2[s] + ad + sea2[i] * c2;
        lg = lg > 0.f ? lg : NEG_SLOPE * lg;
        float ex = __expf(lg);
        den += ex;
        m0 += ex * h2[(size_t)s * C + 0];
        m1 += ex * h2[(size_t)s * C + 1];
    }
    if (lane == 0) {   // self loop
        float lg = a_s2[n] + ad + scal[0] * c2;
        lg = lg > 0.f ? lg : NEG_SLOPE * lg;
        float ex = __expf(lg);
        den += ex;
        m0 += ex * h2[(size_t)n * C + 0];
        m1 += ex * h2[(size_t)n * C + 1];
    }
    for (int off = 32; off; off >>= 1) {
        den += __shfl_down(den, off, 64);
        m0  += __shfl_down(m0, off, 64);
        m1  += __shfl_down(m1, off, 64);
    }
    if (lane == 0) {
        float dn = den + EPSF;
        float o0 = m0 / dn + bias2[0];
        float o1 = m1 / dn + bias2[1];
        float mx = fmaxf(o0, o1);
        float lse = mx + logf(expf(o0 - mx) + expf(o1 - mx));
        out[(size_t)n * C + 0] = o0 - lse;
        out[(size_t)n * C + 1] = o1 - lse;
    }
}

extern "C" void kernel_launch(void* const* d_in, const int* in_sizes, int n_in,
                              void* d_out, int out_size, void* d_ws, size_t ws_size,
                              hipStream_t stream) {
    const float* x        = (const float*)d_in[0];
    const int*   ei       = (const int*)d_in[1];
    const float* ea       = (const float*)d_in[2];
    const float* W1       = (const float*)d_in[3];
    const float* att_src1 = (const float*)d_in[4];
    const float* att_dst1 = (const float*)d_in[5];
    const float* W_edge1  = (const float*)d_in[6];
    const float* att_edge1= (const float*)d_in[7];
    const float* bias1    = (const float*)d_in[8];
    const float* W2       = (const float*)d_in[9];
    const float* att_src2 = (const float*)d_in[10];
    const float* att_dst2 = (const float*)d_in[11];
    const float* W_edge2  = (const float*)d_in[12];
    const float* att_edge2= (const float*)d_in[13];
    const float* bias2    = (const float*)d_in[14];

    const int N  = in_sizes[0] / FIN;
    const int E  = in_sizes[1] / 2;
    const int* srcp = ei;
    const int* dstp = ei + E;
    const int NBUCK = (N + (1 << BSHIFT) - 1) >> BSHIFT;   // 391 for N=100k

    char* wsb = (char*)d_ws;
    size_t off = 0;
    auto alloc = [&](size_t bytes) { void* p = wsb + off; off += (bytes + 255) & ~size_t(255); return p; };
    int*   bcount = (int*)alloc((size_t)NBUCK_MAX * 4);
    float* sum_ea = (float*)alloc(4);
    size_t zbytes = off;                        // bcount + sum_ea must be zeroed
    int*   bbase  = (int*)alloc((size_t)(NBUCK_MAX + 1) * 4);
    int*   bcursor= (int*)alloc((size_t)NBUCK_MAX * 4);
    int*   row    = (int*)alloc((size_t)(N + 1) * 4);
    int2*  sedge  = (int2*)alloc((size_t)(E + 8) * 8);
    float* sea2   = (float*)alloc((size_t)E * 4);
    int2*  staging= (int2*)alloc((size_t)E * 8);
    u16*   h1b    = (u16*)alloc((size_t)N * H * 2);
    u16*   Wt_hi  = (u16*)alloc((size_t)FIN * H * 2);
    u16*   Wt_lo  = (u16*)alloc((size_t)FIN * H * 2);
    float* a_s1   = (float*)alloc((size_t)N * 4);
    float* a_d1   = (float*)alloc((size_t)N * 4);
    float* h2     = (float*)alloc((size_t)N * C * 4);
    float* a_s2   = (float*)alloc((size_t)N * 4);
    float* a_d2   = (float*)alloc((size_t)N * 4);
    float* scal   = (float*)alloc(3 * 4);

    hipMemsetAsync(d_ws, 0, zbytes, stream);

    pre_kernel<<<256, 256, 0, stream>>>(ea, dstp, E, sum_ea, bcount, NBUCK);
    scalars_kernel<<<1, 64, 0, stream>>>(sum_ea, E, W_edge1, att_edge1, W_edge2, att_edge2, scal);
    wprep_kernel<<<(FIN * H + 255) / 256, 256, 0, stream>>>(W1, Wt_hi, Wt_lo);
    bscan_kernel<<<1, 1024, 0, stream>>>(bcount, NBUCK, E, bbase, bcursor, row + N);
    stage_kernel<<<(E + CHUNK - 1) / CHUNK, 256, 0, stream>>>(srcp, dstp, ea, E, bcursor, staging, NBUCK);
    gemm1_mfma_kernel<<<(N + 63) / 64, 256, 0, stream>>>(x, Wt_hi, Wt_lo, att_src1, att_dst1,
                                                         h1b, a_s1, a_d1, N);
    bfin_kernel<<<NBUCK, 256, 0, stream>>>(staging, bbase, scal, a_s1, a_d1, row, sedge, sea2, N);
    agg1_kernel<<<(N + 3) / 4, 256, 0, stream>>>(row, sedge, scal, a_s1, a_d1, h1b,
                                                 bias1, W2, att_src2, att_dst2,
                                                 h2, a_s2, a_d2, N);
    agg2_kernel<<<(N + 3) / 4, 256, 0, stream>>>(row, sedge, sea2, scal, a_s2, a_d2, h2, bias2,
                                                 (float*)d_out, N);
}

// Round 9
// 283.997 us; speedup vs baseline: 1.4319x; 1.1405x over previous
//
#include <hip/hip_runtime.h>
#include <math.h>

#define NEG_SLOPE 0.2f
#define EPSF 1e-16f

constexpr int FIN = 128;
constexpr int H   = 64;
constexpr int C   = 2;
constexpr int BSHIFT = 8;               // nodes per bucket = 256
constexpr int NBUCK_MAX = 1024;         // supports N <= 256k at BSHIFT=8
constexpr int CHUNK = 4096;             // edges per stage block
constexpr int CAP   = 6144;             // max edges per bucket for LDS fast path

typedef short v8s __attribute__((ext_vector_type(8)));
typedef float v4f __attribute__((ext_vector_type(4)));
typedef unsigned short u16;

// round-to-nearest-even fp32 -> bf16 split (hi + lo captures ~17 mantissa bits)
__device__ inline void split_bf16(float v, u16& hi, u16& lo) {
    unsigned u = __float_as_uint(v);
    unsigned r = (u + 0x7FFFu + ((u >> 16) & 1u)) >> 16;
    hi = (u16)r;
    float hf = __uint_as_float(r << 16);
    float l = v - hf;
    unsigned ul = __float_as_uint(l);
    lo = (u16)((ul + 0x7FFFu + ((ul >> 16) & 1u)) >> 16);
}

__device__ inline u16 to_bf16(float v) {
    unsigned u = __float_as_uint(v);
    return (u16)((u + 0x7FFFu + ((u >> 16) & 1u)) >> 16);
}
__device__ inline float blo(int v) { return __uint_as_float((unsigned)v << 16); }
__device__ inline float bhi(int v) { return __uint_as_float((unsigned)v & 0xFFFF0000u); }

// ---------- fused: ea sum + bucket counts + W1 prep ----------
__global__ __launch_bounds__(256) void pre_kernel(const float* __restrict__ ea,
                                                  const int* __restrict__ dst, int E,
                                                  float* __restrict__ out, int* __restrict__ bcount,
                                                  const float* __restrict__ W1,
                                                  u16* __restrict__ Wt_hi, u16* __restrict__ Wt_lo,
                                                  int NBUCK) {
    // W1 prep: first 32 blocks cover 8192 entries
    int gid = blockIdx.x * 256 + threadIdx.x;
    if (gid < FIN * H) {
        int k = gid >> 6, f = gid & 63;       // W1 is [k][f]
        u16 h, l;
        split_bf16(W1[gid], h, l);
        Wt_hi[f * FIN + k] = h;
        Wt_lo[f * FIN + k] = l;
    }
    __shared__ int lh[NBUCK_MAX];
    for (int i = threadIdx.x; i < NBUCK_MAX; i += 256) lh[i] = 0;
    __syncthreads();
    float acc = 0.f;
    for (int e = blockIdx.x * 256 + threadIdx.x; e < E; e += gridDim.x * 256) {
        acc += ea[e];
        atomicAdd(&lh[dst[e] >> BSHIFT], 1);
    }
    for (int off = 32; off; off >>= 1) acc += __shfl_down(acc, off, 64);
    __shared__ float wsum[4];
    int lane = threadIdx.x & 63, wv = threadIdx.x >> 6;
    if (lane == 0) wsum[wv] = acc;
    __syncthreads();
    if (threadIdx.x == 0) atomicAdd(out, wsum[0] + wsum[1] + wsum[2] + wsum[3]);
    for (int i = threadIdx.x; i < NBUCK; i += 256)
        if (lh[i]) atomicAdd(&bcount[i], lh[i]);
}

// ---------- P1: scan bucket counts -> bbase, bcursor; + scalars ----------
__global__ __launch_bounds__(1024) void bscan_kernel(const int* __restrict__ bcount, int NBUCK, int E,
                                                     int* __restrict__ bbase, int* __restrict__ bcursor,
                                                     int* __restrict__ rowN,
                                                     const float* __restrict__ sum_ea,
                                                     const float* __restrict__ W_edge1,
                                                     const float* __restrict__ att_edge1,
                                                     const float* __restrict__ W_edge2,
                                                     const float* __restrict__ att_edge2,
                                                     float* __restrict__ scal) {
    int t = threadIdx.x;
    if (t == 0) {
        float m = *sum_ea / (float)E;
        float c1 = 0.f;
        for (int i = 0; i < H; i++) c1 += W_edge1[i] * att_edge1[i];
        float c2 = 0.f;
        for (int i = 0; i < C; i++) c2 += W_edge2[i] * att_edge2[i];
        scal[0] = m; scal[1] = c1; scal[2] = c2;
    }
    __shared__ int sh[1024];
    int v = (t < NBUCK) ? bcount[t] : 0;
    sh[t] = v;
    __syncthreads();
    for (int off = 1; off < 1024; off <<= 1) {
        int u = (t >= off) ? sh[t - off] : 0;
        __syncthreads();
        sh[t] += u;
        __syncthreads();
    }
    if (t < NBUCK) { bbase[t] = sh[t] - v; bcursor[t] = sh[t] - v; }
    if (t == 0) { bbase[NBUCK] = E; *rowN = E; }
}

// ---------- P2: stage edges into bucket-major order (coalesced runs) ----------
__global__ __launch_bounds__(256) void stage_kernel(
        const int* __restrict__ src, const int* __restrict__ dst, const float* __restrict__ ea,
        int E, int* __restrict__ bcursor, int2* __restrict__ staging, int NBUCK) {
    __shared__ int   cur[NBUCK_MAX];
    __shared__ int   gofs[NBUCK_MAX];
    __shared__ int2  sbuf[CHUNK];
    __shared__ short sbkt[CHUNK];
    __shared__ int   red[256];
    int t = threadIdx.x;
    int base = blockIdx.x * CHUNK;
    int cnt = min(CHUNK, E - base);
    for (int i = t; i < NBUCK_MAX; i += 256) cur[i] = 0;
    __syncthreads();
    for (int i = t; i < cnt; i += 256)
        atomicAdd(&cur[dst[base + i] >> BSHIFT], 1);
    __syncthreads();
    int i0 = t * 4;
    int v0 = cur[i0], v1 = cur[i0 + 1], v2 = cur[i0 + 2], v3 = cur[i0 + 3];
    int s = v0 + v1 + v2 + v3;
    red[t] = s;
    __syncthreads();
    for (int off = 1; off < 256; off <<= 1) {
        int u = (t >= off) ? red[t - off] : 0;
        __syncthreads();
        red[t] += u;
        __syncthreads();
    }
    int run = red[t] - s;
    __syncthreads();
    int p = run;
    if (v0) gofs[i0]     = atomicAdd(&bcursor[i0],     v0) - p;
    cur[i0] = p; p += v0;
    if (v1) gofs[i0 + 1] = atomicAdd(&bcursor[i0 + 1], v1) - p;
    cur[i0 + 1] = p; p += v1;
    if (v2) gofs[i0 + 2] = atomicAdd(&bcursor[i0 + 2], v2) - p;
    cur[i0 + 2] = p; p += v2;
    if (v3) gofs[i0 + 3] = atomicAdd(&bcursor[i0 + 3], v3) - p;
    cur[i0 + 3] = p; p += v3;
    __syncthreads();
    for (int i = t; i < cnt; i += 256) {
        int e = base + i;
        int d = dst[e];
        int b = d >> BSHIFT;
        int slot = atomicAdd(&cur[b], 1);
        sbuf[slot] = make_int2(src[e] | ((d & ((1 << BSHIFT) - 1)) << 20), __float_as_int(ea[e]));
        sbkt[slot] = (short)b;
    }
    __syncthreads();
    for (int j = t; j < cnt; j += 256)
        staging[gofs[sbkt[j]] + j] = sbuf[j];
}

// ---------- layer 1 GEMM via split-bf16 MFMA; h1 stored as bf16 ----------
__global__ __launch_bounds__(256) void gemm1_mfma_kernel(
        const float* __restrict__ x,
        const u16* __restrict__ Wt_hi, const u16* __restrict__ Wt_lo,
        const float* __restrict__ att_src, const float* __restrict__ att_dst,
        u16* __restrict__ h1b, float* __restrict__ a_s, float* __restrict__ a_d, int N) {
    int w = threadIdx.x >> 6, lane = threadIdx.x & 63;
    int m = lane & 15, q = lane >> 4;
    int base = blockIdx.x * 64 + w * 16;
    int nodeA = base + m;
    bool inA = nodeA < N;
    const float* xrow = x + (size_t)nodeA * FIN;

    v8s ah[4], al[4];
    #pragma unroll
    for (int kt = 0; kt < 4; kt++) {
        float xv[8];
        if (inA) {
            const float4* p = (const float4*)(xrow + kt * 32 + q * 8);
            float4 u0 = p[0], u1 = p[1];
            xv[0] = u0.x; xv[1] = u0.y; xv[2] = u0.z; xv[3] = u0.w;
            xv[4] = u1.x; xv[5] = u1.y; xv[6] = u1.z; xv[7] = u1.w;
        } else {
            #pragma unroll
            for (int j = 0; j < 8; j++) xv[j] = 0.f;
        }
        #pragma unroll
        for (int j = 0; j < 8; j++) {
            u16 hb, lb;
            split_bf16(xv[j], hb, lb);
            ah[kt][j] = (short)hb;
            al[kt][j] = (short)lb;
        }
    }

    float ps[4] = {0.f, 0.f, 0.f, 0.f};
    float pd[4] = {0.f, 0.f, 0.f, 0.f};
    #pragma unroll
    for (int ft = 0; ft < 4; ft++) {
        v4f acc = {0.f, 0.f, 0.f, 0.f};
        const u16* bh_base = Wt_hi + (ft * 16 + m) * FIN + q * 8;
        const u16* bl_base = Wt_lo + (ft * 16 + m) * FIN + q * 8;
        #pragma unroll
        for (int kt = 0; kt < 4; kt++) {
            v8s bh = *(const v8s*)(bh_base + kt * 32);
            v8s bl = *(const v8s*)(bl_base + kt * 32);
            acc = __builtin_amdgcn_mfma_f32_16x16x32_bf16(ah[kt], bh, acc, 0, 0, 0);
            acc = __builtin_amdgcn_mfma_f32_16x16x32_bf16(al[kt], bh, acc, 0, 0, 0);
            acc = __builtin_amdgcn_mfma_f32_16x16x32_bf16(ah[kt], bl, acc, 0, 0, 0);
        }
        int f = ft * 16 + m;               // C col
        float asf = att_src[f], adf = att_dst[f];
        #pragma unroll
        for (int r = 0; r < 4; r++) {      // C row = q*4 + r
            int node = base + q * 4 + r;
            if (node < N) h1b[(size_t)node * H + f] = to_bf16(acc[r]);
            ps[r] += acc[r] * asf;
            pd[r] += acc[r] * adf;
        }
    }
    #pragma unroll
    for (int msk = 1; msk < 16; msk <<= 1) {
        #pragma unroll
        for (int r = 0; r < 4; r++) {
            ps[r] += __shfl_xor(ps[r], msk, 64);
            pd[r] += __shfl_xor(pd[r], msk, 64);
        }
    }
    if (m == 0) {
        #pragma unroll
        for (int r = 0; r < 4; r++) {
            int node = base + q * 4 + r;
            if (node < N) { a_s[node] = ps[r]; a_d[node] = pd[r]; }
        }
    }
}

// ---------- P3: per-bucket finalize: CSR rows + LDS-buffered sort + ex1 precompute ----------
__global__ __launch_bounds__(256) void bfin_kernel(
        const int2* __restrict__ staging, const int* __restrict__ bbase,
        const float* __restrict__ scal,
        const float* __restrict__ a_s1, const float* __restrict__ a_d1,
        int* __restrict__ row, int2* __restrict__ sedge, float* __restrict__ sea2, int N) {
    __shared__ int   nh[256];
    __shared__ int   red[256];
    __shared__ int2  ebuf[CAP];    // 48 KB
    __shared__ float abuf[CAP];    // 24 KB
    int b = blockIdx.x, t = threadIdx.x;
    int beg = bbase[b], end = bbase[b + 1];
    int cnt = end - beg;
    int node0 = b << BSHIFT;
    float c1 = scal[1];
    nh[t] = 0;
    __syncthreads();
    for (int i = beg + t; i < end; i += 256)
        atomicAdd(&nh[(unsigned)staging[i].x >> 20], 1);
    __syncthreads();
    int v = nh[t];
    red[t] = v;
    __syncthreads();
    for (int off = 1; off < 256; off <<= 1) {
        int u = (t >= off) ? red[t - off] : 0;
        __syncthreads();
        red[t] += u;
        __syncthreads();
    }
    int excl = red[t] - v;                 // exclusive prefix within bucket
    int node = node0 + t;
    if (node < N) row[node] = beg + excl;
    __syncthreads();
    bool fast = (cnt <= CAP);
    nh[t] = fast ? excl : beg + excl;      // relative (LDS) or absolute (fallback) cursor
    __syncthreads();
    for (int i = beg + t; i < end; i += 256) {
        int2 r = staging[i];
        int dlow = (unsigned)r.x >> 20;
        int sn = r.x & 0xFFFFF;
        float eav = __int_as_float(r.y);
        float lg = a_s1[sn] + a_d1[node0 + dlow] + eav * c1;
        lg = lg > 0.f ? lg : NEG_SLOPE * lg;
        float ex = __expf(lg);
        int pos = atomicAdd(&nh[dlow], 1);
        if (fast) {
            ebuf[pos] = make_int2(sn, __float_as_int(ex));
            abuf[pos] = eav;
        } else {
            sedge[pos] = make_int2(sn, __float_as_int(ex));
            sea2[pos] = eav;
        }
    }
    __syncthreads();
    if (fast) {
        for (int j = t; j < cnt; j += 256) {
            sedge[beg + j] = ebuf[j];
            sea2[beg + j]  = abuf[j];
        }
    }
}

// ---------- layer 1 aggregation: 8-lane group per dst node + gemm2 fused ----------
__global__ __launch_bounds__(256) void agg1_kernel(
        const int* __restrict__ row, const int2* __restrict__ sedge,
        const float* __restrict__ scal,
        const float* __restrict__ a_s, const float* __restrict__ a_d,
        const u16* __restrict__ h1b,
        const float* __restrict__ bias1, const float* __restrict__ W2,
        const float* __restrict__ att_src2, const float* __restrict__ att_dst2,
        float* __restrict__ h2, float* __restrict__ a_s2, float* __restrict__ a_d2,
        int N) {
    int wv = threadIdx.x >> 6;
    int lane = threadIdx.x & 63;
    int g  = lane >> 3;        // node within wave (0..7)
    int fl = lane & 7;         // feature block: features fl*8 .. fl*8+7
    int n = blockIdx.x * 32 + wv * 8 + g;
    if (n >= N) return;
    int beg = row[n], end = row[n + 1];
    float den = 0.f;           // redundantly computed per lane in group
    float acc[8] = {0.f, 0.f, 0.f, 0.f, 0.f, 0.f, 0.f, 0.f};
    const u16* hrow = h1b + fl * 8;
    int i = beg;
    for (; i + 2 <= end; i += 2) {
        int2 e0 = sedge[i], e1 = sedge[i + 1];
        int4 h0 = *(const int4*)(hrow + (size_t)e0.x * H);
        int4 h1v = *(const int4*)(hrow + (size_t)e1.x * H);
        float x0 = __int_as_float(e0.y), x1 = __int_as_float(e1.y);
        den += x0 + x1;
        acc[0] += x0 * blo(h0.x); acc[1] += x0 * bhi(h0.x);
        acc[2] += x0 * blo(h0.y); acc[3] += x0 * bhi(h0.y);
        acc[4] += x0 * blo(h0.z); acc[5] += x0 * bhi(h0.z);
        acc[6] += x0 * blo(h0.w); acc[7] += x0 * bhi(h0.w);
        acc[0] += x1 * blo(h1v.x); acc[1] += x1 * bhi(h1v.x);
        acc[2] += x1 * blo(h1v.y); acc[3] += x1 * bhi(h1v.y);
        acc[4] += x1 * blo(h1v.z); acc[5] += x1 * bhi(h1v.z);
        acc[6] += x1 * blo(h1v.w); acc[7] += x1 * bhi(h1v.w);
    }
    if (i < end) {
        int2 e0 = sedge[i];
        int4 h0 = *(const int4*)(hrow + (size_t)e0.x * H);
        float x0 = __int_as_float(e0.y);
        den += x0;
        acc[0] += x0 * blo(h0.x); acc[1] += x0 * bhi(h0.x);
        acc[2] += x0 * blo(h0.y); acc[3] += x0 * bhi(h0.y);
        acc[4] += x0 * blo(h0.z); acc[5] += x0 * bhi(h0.z);
        acc[6] += x0 * blo(h0.w); acc[7] += x0 * bhi(h0.w);
    }
    // self loop (src = dst = n, edge_attr = mean)
    {
        float lg = a_s[n] + a_d[n] + scal[0] * scal[1];
        lg = lg > 0.f ? lg : NEG_SLOPE * lg;
        float ex = __expf(lg);
        int4 hs = *(const int4*)(hrow + (size_t)n * H);
        den += ex;
        acc[0] += ex * blo(hs.x); acc[1] += ex * bhi(hs.x);
        acc[2] += ex * blo(hs.y); acc[3] += ex * bhi(hs.y);
        acc[4] += ex * blo(hs.z); acc[5] += ex * bhi(hs.z);
        acc[6] += ex * blo(hs.w); acc[7] += ex * bhi(hs.w);
    }
    // epilogue: divide, bias, relu, fused gemm2 over this lane's 8 features
    float inv = 1.f / (den + EPSF);
    float p0 = 0.f, p1 = 0.f;
    #pragma unroll
    for (int k = 0; k < 8; k++) {
        int f = fl * 8 + k;
        float hr = acc[k] * inv + bias1[f];
        hr = fmaxf(hr, 0.f);
        p0 += hr * W2[f * C + 0];
        p1 += hr * W2[f * C + 1];
    }
    // reduce over the 8 feature blocks (group-local lanes, bits 0..2)
    #pragma unroll
    for (int msk = 1; msk < 8; msk <<= 1) {
        p0 += __shfl_xor(p0, msk, 64);
        p1 += __shfl_xor(p1, msk, 64);
    }
    if (fl == 0) {
        h2[(size_t)n * C + 0] = p0;
        h2[(size_t)n * C + 1] = p1;
        a_s2[n] = p0 * att_src2[0] + p1 * att_src2[1];
        a_d2[n] = p0 * att_dst2[0] + p1 * att_dst2[1];
    }
}

// ---------- layer 2 aggregation: 8-lane group per dst node + log_softmax ----------
__global__ __launch_bounds__(256) void agg2_kernel(
        const int* __restrict__ row, const int2* __restrict__ sedge, const float* __restrict__ sea2,
        const float* __restrict__ scal,
        const float* __restrict__ a_s2, const float* __restrict__ a_d2,
        const float* __restrict__ h2, const float* __restrict__ bias2,
        float* __restrict__ out, int N) {
    int wv = threadIdx.x >> 6;
    int lane = threadIdx.x & 63;
    int g  = lane >> 3;
    int fl = lane & 7;
    int n = blockIdx.x * 32 + wv * 8 + g;
    if (n >= N) return;
    float c2 = scal[2];
    float ad = a_d2[n];
    int beg = row[n], end = row[n + 1];
    float den = 0.f, m0 = 0.f, m1 = 0.f;
    for (int i = beg + fl; i < end; i += 8) {
        int s = sedge[i].x;
        float lg = a_s2[s] + ad + sea2[i] * c2;
        lg = lg > 0.f ? lg : NEG_SLOPE * lg;
        float ex = __expf(lg);
        den += ex;
        m0 += ex * h2[(size_t)s * C + 0];
        m1 += ex * h2[(size_t)s * C + 1];
    }
    if (fl == 0) {   // self loop
        float lg = a_s2[n] + ad + scal[0] * c2;
        lg = lg > 0.f ? lg : NEG_SLOPE * lg;
        float ex = __expf(lg);
        den += ex;
        m0 += ex * h2[(size_t)n * C + 0];
        m1 += ex * h2[(size_t)n * C + 1];
    }
    #pragma unroll
    for (int msk = 1; msk < 8; msk <<= 1) {
        den += __shfl_xor(den, msk, 64);
        m0  += __shfl_xor(m0, msk, 64);
        m1  += __shfl_xor(m1, msk, 64);
    }
    if (fl == 0) {
        float dn = den + EPSF;
        float o0 = m0 / dn + bias2[0];
        float o1 = m1 / dn + bias2[1];
        float mx = fmaxf(o0, o1);
        float lse = mx + logf(expf(o0 - mx) + expf(o1 - mx));
        out[(size_t)n * C + 0] = o0 - lse;
        out[(size_t)n * C + 1] = o1 - lse;
    }
}

extern "C" void kernel_launch(void* const* d_in, const int* in_sizes, int n_in,
                              void* d_out, int out_size, void* d_ws, size_t ws_size,
                              hipStream_t stream) {
    const float* x        = (const float*)d_in[0];
    const int*   ei       = (const int*)d_in[1];
    const float* ea       = (const float*)d_in[2];
    const float* W1       = (const float*)d_in[3];
    const float* att_src1 = (const float*)d_in[4];
    const float* att_dst1 = (const float*)d_in[5];
    const float* W_edge1  = (const float*)d_in[6];
    const float* att_edge1= (const float*)d_in[7];
    const float* bias1    = (const float*)d_in[8];
    const float* W2       = (const float*)d_in[9];
    const float* att_src2 = (const float*)d_in[10];
    const float* att_dst2 = (const float*)d_in[11];
    const float* W_edge2  = (const float*)d_in[12];
    const float* att_edge2= (const float*)d_in[13];
    const float* bias2    = (const float*)d_in[14];

    const int N  = in_sizes[0] / FIN;
    const int E  = in_sizes[1] / 2;
    const int* srcp = ei;
    const int* dstp = ei + E;
    const int NBUCK = (N + (1 << BSHIFT) - 1) >> BSHIFT;   // 391 for N=100k

    char* wsb = (char*)d_ws;
    size_t off = 0;
    auto alloc = [&](size_t bytes) { void* p = wsb + off; off += (bytes + 255) & ~size_t(255); return p; };
    int*   bcount = (int*)alloc((size_t)NBUCK_MAX * 4);
    float* sum_ea = (float*)alloc(4);
    size_t zbytes = off;                        // bcount + sum_ea must be zeroed
    int*   bbase  = (int*)alloc((size_t)(NBUCK_MAX + 1) * 4);
    int*   bcursor= (int*)alloc((size_t)NBUCK_MAX * 4);
    int*   row    = (int*)alloc((size_t)(N + 1) * 4);
    int2*  sedge  = (int2*)alloc((size_t)(E + 8) * 8);
    float* sea2   = (float*)alloc((size_t)E * 4);
    int2*  staging= (int2*)alloc((size_t)E * 8);
    u16*   h1b    = (u16*)alloc((size_t)N * H * 2);
    u16*   Wt_hi  = (u16*)alloc((size_t)FIN * H * 2);
    u16*   Wt_lo  = (u16*)alloc((size_t)FIN * H * 2);
    float* a_s1   = (float*)alloc((size_t)N * 4);
    float* a_d1   = (float*)alloc((size_t)N * 4);
    float* h2     = (float*)alloc((size_t)N * C * 4);
    float* a_s2   = (float*)alloc((size_t)N * 4);
    float* a_d2   = (float*)alloc((size_t)N * 4);
    float* scal   = (float*)alloc(3 * 4);

    hipMemsetAsync(d_ws, 0, zbytes, stream);

    pre_kernel<<<256, 256, 0, stream>>>(ea, dstp, E, sum_ea, bcount, W1, Wt_hi, Wt_lo, NBUCK);
    bscan_kernel<<<1, 1024, 0, stream>>>(bcount, NBUCK, E, bbase, bcursor, row + N,
                                         sum_ea, W_edge1, att_edge1, W_edge2, att_edge2, scal);
    stage_kernel<<<(E + CHUNK - 1) / CHUNK, 256, 0, stream>>>(srcp, dstp, ea, E, bcursor, staging, NBUCK);
    gemm1_mfma_kernel<<<(N + 63) / 64, 256, 0, stream>>>(x, Wt_hi, Wt_lo, att_src1, att_dst1,
                                                         h1b, a_s1, a_d1, N);
    bfin_kernel<<<NBUCK, 256, 0, stream>>>(staging, bbase, scal, a_s1, a_d1, row, sedge, sea2, N);
    agg1_kernel<<<(N + 31) / 32, 256, 0, stream>>>(row, sedge, scal, a_s1, a_d1, h1b,
                                                   bias1, W2, att_src2, att_dst2,
                                                   h2, a_s2, a_d2, N);
    agg2_kernel<<<(N + 31) / 32, 256, 0, stream>>>(row, sedge, sea2, scal, a_s2, a_d2, h2, bias2,
                                                   (float*)d_out, N);
}

// Round 10
// 253.445 us; speedup vs baseline: 1.6045x; 1.1205x over previous
//
#include <hip/hip_runtime.h>
#include <math.h>

#define NEG_SLOPE 0.2f
#define EPSF 1e-16f

constexpr int FIN = 128;
constexpr int H   = 64;
constexpr int C   = 2;
constexpr int BSHIFT = 8;               // nodes per bucket = 256
constexpr int NBUCK_MAX = 1024;         // supports N <= 256k at BSHIFT=8
constexpr int CHUNK = 4096;             // edges per stage block
constexpr int CAP   = 6144;             // max edges per bucket for LDS fast path

typedef short v8s __attribute__((ext_vector_type(8)));
typedef float v4f __attribute__((ext_vector_type(4)));
typedef unsigned short u16;

// round-to-nearest-even fp32 -> bf16 split (hi + lo captures ~17 mantissa bits)
__device__ inline void split_bf16(float v, u16& hi, u16& lo) {
    unsigned u = __float_as_uint(v);
    unsigned r = (u + 0x7FFFu + ((u >> 16) & 1u)) >> 16;
    hi = (u16)r;
    float hf = __uint_as_float(r << 16);
    float l = v - hf;
    unsigned ul = __float_as_uint(l);
    lo = (u16)((ul + 0x7FFFu + ((ul >> 16) & 1u)) >> 16);
}

__device__ inline u16 to_bf16(float v) {
    unsigned u = __float_as_uint(v);
    return (u16)((u + 0x7FFFu + ((u >> 16) & 1u)) >> 16);
}
__device__ inline float blo(int v) { return __uint_as_float((unsigned)v << 16); }
__device__ inline float bhi(int v) { return __uint_as_float((unsigned)v & 0xFFFF0000u); }

// ---------- pre: one chunk per block. ea sum + per-chunk histogram + W1 prep ----------
__global__ __launch_bounds__(256) void pre_kernel(const float* __restrict__ ea,
                                                  const int* __restrict__ dst, int E,
                                                  float* __restrict__ sum_ea, int* __restrict__ cnt,
                                                  const float* __restrict__ W1,
                                                  u16* __restrict__ Wt_hi, u16* __restrict__ Wt_lo,
                                                  int NBUCK) {
    int c = blockIdx.x, t = threadIdx.x;
    int gid = c * 256 + t;
    if (gid < FIN * H) {                      // W1 prep: first 32 blocks
        int k = gid >> 6, f = gid & 63;       // W1 is [k][f]
        u16 h, l;
        split_bf16(W1[gid], h, l);
        Wt_hi[f * FIN + k] = h;
        Wt_lo[f * FIN + k] = l;
    }
    __shared__ int lh[NBUCK_MAX];
    for (int i = t; i < NBUCK_MAX; i += 256) lh[i] = 0;
    __syncthreads();
    int base = c * CHUNK;
    int cntE = min(CHUNK, E - base);
    float acc = 0.f;
    for (int i = t; i < cntE; i += 256) {
        int e = base + i;
        acc += ea[e];
        atomicAdd(&lh[dst[e] >> BSHIFT], 1);
    }
    for (int off = 32; off; off >>= 1) acc += __shfl_down(acc, off, 64);
    __shared__ float wsum[4];
    int lane = t & 63, wv = t >> 6;
    if (lane == 0) wsum[wv] = acc;
    __syncthreads();                          // covers lh atomics + wsum
    if (t == 0) atomicAdd(sum_ea, wsum[0] + wsum[1] + wsum[2] + wsum[3]);
    for (int i = t; i < NBUCK; i += 256)
        cnt[(size_t)c * NBUCK + i] = lh[i];
}

// ---------- soff: per-bucket scan over chunks -> poff[b][c], bcount[b] ----------
__global__ __launch_bounds__(256) void soff_kernel(const int* __restrict__ cnt,
                                                   int NBUCK, int NCHUNK,
                                                   int* __restrict__ bcount, int* __restrict__ poff) {
    int b = blockIdx.x, t = threadIdx.x;
    int per = (NCHUNK + 255) / 256;           // chunks per thread (2 for NCHUNK=391)
    int v[8];                                 // supports NCHUNK <= 2048
    int s = 0;
    for (int j = 0; j < per; j++) {
        int c = t * per + j;
        v[j] = (c < NCHUNK) ? cnt[(size_t)c * NBUCK + b] : 0;
        s += v[j];
    }
    __shared__ int red[256];
    red[t] = s;
    __syncthreads();
    for (int off = 1; off < 256; off <<= 1) {
        int u = (t >= off) ? red[t - off] : 0;
        __syncthreads();
        red[t] += u;
        __syncthreads();
    }
    int run = red[t] - s;
    for (int j = 0; j < per; j++) {
        int c = t * per + j;
        if (c < NCHUNK) poff[(size_t)b * NCHUNK + c] = run;
        run += v[j];
    }
    if (t == 255) bcount[b] = red[255];
}

// ---------- P1: scan bucket counts -> bbase; + scalars ----------
__global__ __launch_bounds__(1024) void bscan_kernel(const int* __restrict__ bcount, int NBUCK, int E,
                                                     int* __restrict__ bbase,
                                                     int* __restrict__ rowN,
                                                     const float* __restrict__ sum_ea,
                                                     const float* __restrict__ W_edge1,
                                                     const float* __restrict__ att_edge1,
                                                     const float* __restrict__ W_edge2,
                                                     const float* __restrict__ att_edge2,
                                                     float* __restrict__ scal) {
    int t = threadIdx.x;
    if (t == 0) {
        float m = *sum_ea / (float)E;
        float c1 = 0.f;
        for (int i = 0; i < H; i++) c1 += W_edge1[i] * att_edge1[i];
        float c2 = 0.f;
        for (int i = 0; i < C; i++) c2 += W_edge2[i] * att_edge2[i];
        scal[0] = m; scal[1] = c1; scal[2] = c2;
    }
    __shared__ int sh[1024];
    int v = (t < NBUCK) ? bcount[t] : 0;
    sh[t] = v;
    __syncthreads();
    for (int off = 1; off < 1024; off <<= 1) {
        int u = (t >= off) ? sh[t - off] : 0;
        __syncthreads();
        sh[t] += u;
        __syncthreads();
    }
    if (t < NBUCK) bbase[t] = sh[t] - v;
    if (t == 0) { bbase[NBUCK] = E; *rowN = E; }
}

// ---------- P2: stage edges into bucket-major order (deterministic offsets, no atomics) ----------
__global__ __launch_bounds__(256) void stage_kernel(
        const int* __restrict__ src, const int* __restrict__ dst, const float* __restrict__ ea,
        int E, const int* __restrict__ cnt, const int* __restrict__ poff,
        const int* __restrict__ bbase,
        int2* __restrict__ staging, int NBUCK, int NCHUNK) {
    __shared__ int   cur[NBUCK_MAX];
    __shared__ int   gofs[NBUCK_MAX];
    __shared__ int2  sbuf[CHUNK];
    __shared__ short sbkt[CHUNK];
    __shared__ int   red[256];
    int t = threadIdx.x;
    int c = blockIdx.x;
    int base = c * CHUNK;
    int cntE = min(CHUNK, E - base);
    // local histogram from cnt (no dst re-read)
    int i0 = t * 4;
    int h[4];
    #pragma unroll
    for (int j = 0; j < 4; j++) {
        int i = i0 + j;
        h[j] = (i < NBUCK) ? cnt[(size_t)c * NBUCK + i] : 0;
    }
    int s = h[0] + h[1] + h[2] + h[3];
    red[t] = s;
    __syncthreads();
    for (int off = 1; off < 256; off <<= 1) {
        int u = (t >= off) ? red[t - off] : 0;
        __syncthreads();
        red[t] += u;
        __syncthreads();
    }
    int p = red[t] - s;                       // local exclusive prefix
    #pragma unroll
    for (int j = 0; j < 4; j++) {
        int i = i0 + j;
        if (i < NBUCK) {
            if (h[j]) gofs[i] = bbase[i] + poff[(size_t)i * NCHUNK + c] - p;
            cur[i] = p;
        }
        p += h[j];
    }
    __syncthreads();
    // reorder into LDS
    for (int i = t; i < cntE; i += 256) {
        int e = base + i;
        int d = dst[e];
        int b = d >> BSHIFT;
        int slot = atomicAdd(&cur[b], 1);
        sbuf[slot] = make_int2(src[e] | ((d & ((1 << BSHIFT) - 1)) << 20), __float_as_int(ea[e]));
        sbkt[slot] = (short)b;
    }
    __syncthreads();
    // coalesced write-out
    for (int j = t; j < cntE; j += 256)
        staging[gofs[sbkt[j]] + j] = sbuf[j];
}

// ---------- layer 1 GEMM via split-bf16 MFMA; h1 stored as bf16 ----------
__global__ __launch_bounds__(256) void gemm1_mfma_kernel(
        const float* __restrict__ x,
        const u16* __restrict__ Wt_hi, const u16* __restrict__ Wt_lo,
        const float* __restrict__ att_src, const float* __restrict__ att_dst,
        u16* __restrict__ h1b, float* __restrict__ a_s, float* __restrict__ a_d, int N) {
    int w = threadIdx.x >> 6, lane = threadIdx.x & 63;
    int m = lane & 15, q = lane >> 4;
    int base = blockIdx.x * 64 + w * 16;
    int nodeA = base + m;
    bool inA = nodeA < N;
    const float* xrow = x + (size_t)nodeA * FIN;

    v8s ah[4], al[4];
    #pragma unroll
    for (int kt = 0; kt < 4; kt++) {
        float xv[8];
        if (inA) {
            const float4* p = (const float4*)(xrow + kt * 32 + q * 8);
            float4 u0 = p[0], u1 = p[1];
            xv[0] = u0.x; xv[1] = u0.y; xv[2] = u0.z; xv[3] = u0.w;
            xv[4] = u1.x; xv[5] = u1.y; xv[6] = u1.z; xv[7] = u1.w;
        } else {
            #pragma unroll
            for (int j = 0; j < 8; j++) xv[j] = 0.f;
        }
        #pragma unroll
        for (int j = 0; j < 8; j++) {
            u16 hb, lb;
            split_bf16(xv[j], hb, lb);
            ah[kt][j] = (short)hb;
            al[kt][j] = (short)lb;
        }
    }

    float ps[4] = {0.f, 0.f, 0.f, 0.f};
    float pd[4] = {0.f, 0.f, 0.f, 0.f};
    #pragma unroll
    for (int ft = 0; ft < 4; ft++) {
        v4f acc = {0.f, 0.f, 0.f, 0.f};
        const u16* bh_base = Wt_hi + (ft * 16 + m) * FIN + q * 8;
        const u16* bl_base = Wt_lo + (ft * 16 + m) * FIN + q * 8;
        #pragma unroll
        for (int kt = 0; kt < 4; kt++) {
            v8s bh = *(const v8s*)(bh_base + kt * 32);
            v8s bl = *(const v8s*)(bl_base + kt * 32);
            acc = __builtin_amdgcn_mfma_f32_16x16x32_bf16(ah[kt], bh, acc, 0, 0, 0);
            acc = __builtin_amdgcn_mfma_f32_16x16x32_bf16(al[kt], bh, acc, 0, 0, 0);
            acc = __builtin_amdgcn_mfma_f32_16x16x32_bf16(ah[kt], bl, acc, 0, 0, 0);
        }
        int f = ft * 16 + m;               // C col
        float asf = att_src[f], adf = att_dst[f];
        #pragma unroll
        for (int r = 0; r < 4; r++) {      // C row = q*4 + r
            int node = base + q * 4 + r;
            if (node < N) h1b[(size_t)node * H + f] = to_bf16(acc[r]);
            ps[r] += acc[r] * asf;
            pd[r] += acc[r] * adf;
        }
    }
    #pragma unroll
    for (int msk = 1; msk < 16; msk <<= 1) {
        #pragma unroll
        for (int r = 0; r < 4; r++) {
            ps[r] += __shfl_xor(ps[r], msk, 64);
            pd[r] += __shfl_xor(pd[r], msk, 64);
        }
    }
    if (m == 0) {
        #pragma unroll
        for (int r = 0; r < 4; r++) {
            int node = base + q * 4 + r;
            if (node < N) { a_s[node] = ps[r]; a_d[node] = pd[r]; }
        }
    }
}

// ---------- P3: per-bucket finalize: CSR rows + LDS-buffered sort + ex1 precompute ----------
__global__ __launch_bounds__(256) void bfin_kernel(
        const int2* __restrict__ staging, const int* __restrict__ bbase,
        const float* __restrict__ scal,
        const float* __restrict__ a_s1, const float* __restrict__ a_d1,
        int* __restrict__ row, int2* __restrict__ sedge, float* __restrict__ sea2, int N) {
    __shared__ int   nh[256];
    __shared__ int   red[256];
    __shared__ int2  ebuf[CAP];    // 48 KB
    __shared__ float abuf[CAP];    // 24 KB
    int b = blockIdx.x, t = threadIdx.x;
    int beg = bbase[b], end = bbase[b + 1];
    int cnt = end - beg;
    int node0 = b << BSHIFT;
    float c1 = scal[1];
    nh[t] = 0;
    __syncthreads();
    for (int i = beg + t; i < end; i += 256)
        atomicAdd(&nh[(unsigned)staging[i].x >> 20], 1);
    __syncthreads();
    int v = nh[t];
    red[t] = v;
    __syncthreads();
    for (int off = 1; off < 256; off <<= 1) {
        int u = (t >= off) ? red[t - off] : 0;
        __syncthreads();
        red[t] += u;
        __syncthreads();
    }
    int excl = red[t] - v;                 // exclusive prefix within bucket
    int node = node0 + t;
    if (node < N) row[node] = beg + excl;
    __syncthreads();
    bool fast = (cnt <= CAP);
    nh[t] = fast ? excl : beg + excl;      // relative (LDS) or absolute (fallback) cursor
    __syncthreads();
    for (int i = beg + t; i < end; i += 256) {
        int2 r = staging[i];
        int dlow = (unsigned)r.x >> 20;
        int sn = r.x & 0xFFFFF;
        float eav = __int_as_float(r.y);
        float lg = a_s1[sn] + a_d1[node0 + dlow] + eav * c1;
        lg = lg > 0.f ? lg : NEG_SLOPE * lg;
        float ex = __expf(lg);
        int pos = atomicAdd(&nh[dlow], 1);
        if (fast) {
            ebuf[pos] = make_int2(sn, __float_as_int(ex));
            abuf[pos] = eav;
        } else {
            sedge[pos] = make_int2(sn, __float_as_int(ex));
            sea2[pos] = eav;
        }
    }
    __syncthreads();
    if (fast) {
        for (int j = t; j < cnt; j += 256) {
            sedge[beg + j] = ebuf[j];
            sea2[beg + j]  = abuf[j];
        }
    }
}

// ---------- layer 1 aggregation: 8-lane group per dst node + gemm2 fused ----------
__global__ __launch_bounds__(256) void agg1_kernel(
        const int* __restrict__ row, const int2* __restrict__ sedge,
        const float* __restrict__ scal,
        const float* __restrict__ a_s, const float* __restrict__ a_d,
        const u16* __restrict__ h1b,
        const float* __restrict__ bias1, const float* __restrict__ W2,
        const float* __restrict__ att_src2, const float* __restrict__ att_dst2,
        float* __restrict__ h2, float* __restrict__ a_s2, float* __restrict__ a_d2,
        int N) {
    int wv = threadIdx.x >> 6;
    int lane = threadIdx.x & 63;
    int g  = lane >> 3;        // node within wave (0..7)
    int fl = lane & 7;         // feature block: features fl*8 .. fl*8+7
    int n = blockIdx.x * 32 + wv * 8 + g;
    if (n >= N) return;
    int beg = row[n], end = row[n + 1];
    float den = 0.f;           // redundantly computed per lane in group
    float acc[8] = {0.f, 0.f, 0.f, 0.f, 0.f, 0.f, 0.f, 0.f};
    const u16* hrow = h1b + fl * 8;
    int i = beg;
    for (; i + 2 <= end; i += 2) {
        int2 e0 = sedge[i], e1 = sedge[i + 1];
        int4 h0 = *(const int4*)(hrow + (size_t)e0.x * H);
        int4 h1v = *(const int4*)(hrow + (size_t)e1.x * H);
        float x0 = __int_as_float(e0.y), x1 = __int_as_float(e1.y);
        den += x0 + x1;
        acc[0] += x0 * blo(h0.x); acc[1] += x0 * bhi(h0.x);
        acc[2] += x0 * blo(h0.y); acc[3] += x0 * bhi(h0.y);
        acc[4] += x0 * blo(h0.z); acc[5] += x0 * bhi(h0.z);
        acc[6] += x0 * blo(h0.w); acc[7] += x0 * bhi(h0.w);
        acc[0] += x1 * blo(h1v.x); acc[1] += x1 * bhi(h1v.x);
        acc[2] += x1 * blo(h1v.y); acc[3] += x1 * bhi(h1v.y);
        acc[4] += x1 * blo(h1v.z); acc[5] += x1 * bhi(h1v.z);
        acc[6] += x1 * blo(h1v.w); acc[7] += x1 * bhi(h1v.w);
    }
    if (i < end) {
        int2 e0 = sedge[i];
        int4 h0 = *(const int4*)(hrow + (size_t)e0.x * H);
        float x0 = __int_as_float(e0.y);
        den += x0;
        acc[0] += x0 * blo(h0.x); acc[1] += x0 * bhi(h0.x);
        acc[2] += x0 * blo(h0.y); acc[3] += x0 * bhi(h0.y);
        acc[4] += x0 * blo(h0.z); acc[5] += x0 * bhi(h0.z);
        acc[6] += x0 * blo(h0.w); acc[7] += x0 * bhi(h0.w);
    }
    // self loop (src = dst = n, edge_attr = mean)
    {
        float lg = a_s[n] + a_d[n] + scal[0] * scal[1];
        lg = lg > 0.f ? lg : NEG_SLOPE * lg;
        float ex = __expf(lg);
        int4 hs = *(const int4*)(hrow + (size_t)n * H);
        den += ex;
        acc[0] += ex * blo(hs.x); acc[1] += ex * bhi(hs.x);
        acc[2] += ex * blo(hs.y); acc[3] += ex * bhi(hs.y);
        acc[4] += ex * blo(hs.z); acc[5] += ex * bhi(hs.z);
        acc[6] += ex * blo(hs.w); acc[7] += ex * bhi(hs.w);
    }
    // epilogue: divide, bias, relu, fused gemm2 over this lane's 8 features
    float inv = 1.f / (den + EPSF);
    float p0 = 0.f, p1 = 0.f;
    #pragma unroll
    for (int k = 0; k < 8; k++) {
        int f = fl * 8 + k;
        float hr = acc[k] * inv + bias1[f];
        hr = fmaxf(hr, 0.f);
        p0 += hr * W2[f * C + 0];
        p1 += hr * W2[f * C + 1];
    }
    // reduce over the 8 feature blocks (group-local lanes, bits 0..2)
    #pragma unroll
    for (int msk = 1; msk < 8; msk <<= 1) {
        p0 += __shfl_xor(p0, msk, 64);
        p1 += __shfl_xor(p1, msk, 64);
    }
    if (fl == 0) {
        h2[(size_t)n * C + 0] = p0;
        h2[(size_t)n * C + 1] = p1;
        a_s2[n] = p0 * att_src2[0] + p1 * att_src2[1];
        a_d2[n] = p0 * att_dst2[0] + p1 * att_dst2[1];
    }
}

// ---------- layer 2 aggregation: 8-lane group per dst node + log_softmax ----------
__global__ __launch_bounds__(256) void agg2_kernel(
        const int* __restrict__ row, const int2* __restrict__ sedge, const float* __restrict__ sea2,
        const float* __restrict__ scal,
        const float* __restrict__ a_s2, const float* __restrict__ a_d2,
        const float* __restrict__ h2, const float* __restrict__ bias2,
        float* __restrict__ out, int N) {
    int wv = threadIdx.x >> 6;
    int lane = threadIdx.x & 63;
    int g  = lane >> 3;
    int fl = lane & 7;
    int n = blockIdx.x * 32 + wv * 8 + g;
    if (n >= N) return;
    float c2 = scal[2];
    float ad = a_d2[n];
    int beg = row[n], end = row[n + 1];
    float den = 0.f, m0 = 0.f, m1 = 0.f;
    for (int i = beg + fl; i < end; i += 8) {
        int s = sedge[i].x;
        float lg = a_s2[s] + ad + sea2[i] * c2;
        lg = lg > 0.f ? lg : NEG_SLOPE * lg;
        float ex = __expf(lg);
        den += ex;
        m0 += ex * h2[(size_t)s * C + 0];
        m1 += ex * h2[(size_t)s * C + 1];
    }
    if (fl == 0) {   // self loop
        float lg = a_s2[n] + ad + scal[0] * c2;
        lg = lg > 0.f ? lg : NEG_SLOPE * lg;
        float ex = __expf(lg);
        den += ex;
        m0 += ex * h2[(size_t)n * C + 0];
        m1 += ex * h2[(size_t)n * C + 1];
    }
    #pragma unroll
    for (int msk = 1; msk < 8; msk <<= 1) {
        den += __shfl_xor(den, msk, 64);
        m0  += __shfl_xor(m0, msk, 64);
        m1  += __shfl_xor(m1, msk, 64);
    }
    if (fl == 0) {
        float dn = den + EPSF;
        float o0 = m0 / dn + bias2[0];
        float o1 = m1 / dn + bias2[1];
        float mx = fmaxf(o0, o1);
        float lse = mx + logf(expf(o0 - mx) + expf(o1 - mx));
        out[(size_t)n * C + 0] = o0 - lse;
        out[(size_t)n * C + 1] = o1 - lse;
    }
}

extern "C" void kernel_launch(void* const* d_in, const int* in_sizes, int n_in,
                              void* d_out, int out_size, void* d_ws, size_t ws_size,
                              hipStream_t stream) {
    const float* x        = (const float*)d_in[0];
    const int*   ei       = (const int*)d_in[1];
    const float* ea       = (const float*)d_in[2];
    const float* W1       = (const float*)d_in[3];
    const float* att_src1 = (const float*)d_in[4];
    const float* att_dst1 = (const float*)d_in[5];
    const float* W_edge1  = (const float*)d_in[6];
    const float* att_edge1= (const float*)d_in[7];
    const float* bias1    = (const float*)d_in[8];
    const float* W2       = (const float*)d_in[9];
    const float* att_src2 = (const float*)d_in[10];
    const float* att_dst2 = (const float*)d_in[11];
    const float* W_edge2  = (const float*)d_in[12];
    const float* att_edge2= (const float*)d_in[13];
    const float* bias2    = (const float*)d_in[14];

    const int N  = in_sizes[0] / FIN;
    const int E  = in_sizes[1] / 2;
    const int* srcp = ei;
    const int* dstp = ei + E;
    const int NBUCK  = (N + (1 << BSHIFT) - 1) >> BSHIFT;   // 391 for N=100k
    const int NCHUNK = (E + CHUNK - 1) / CHUNK;             // 391 for E=1.6M

    char* wsb = (char*)d_ws;
    size_t off = 0;
    auto alloc = [&](size_t bytes) { void* p = wsb + off; off += (bytes + 255) & ~size_t(255); return p; };
    float* sum_ea = (float*)alloc(4);
    size_t zbytes = off;                        // only sum_ea must be zeroed
    int*   bcount = (int*)alloc((size_t)NBUCK_MAX * 4);
    int*   bbase  = (int*)alloc((size_t)(NBUCK_MAX + 1) * 4);
    int*   cnt    = (int*)alloc((size_t)NCHUNK * NBUCK * 4);
    int*   poff   = (int*)alloc((size_t)NBUCK * NCHUNK * 4);
    int*   row    = (int*)alloc((size_t)(N + 1) * 4);
    int2*  sedge  = (int2*)alloc((size_t)(E + 8) * 8);
    float* sea2   = (float*)alloc((size_t)E * 4);
    int2*  staging= (int2*)alloc((size_t)E * 8);
    u16*   h1b    = (u16*)alloc((size_t)N * H * 2);
    u16*   Wt_hi  = (u16*)alloc((size_t)FIN * H * 2);
    u16*   Wt_lo  = (u16*)alloc((size_t)FIN * H * 2);
    float* a_s1   = (float*)alloc((size_t)N * 4);
    float* a_d1   = (float*)alloc((size_t)N * 4);
    float* h2     = (float*)alloc((size_t)N * C * 4);
    float* a_s2   = (float*)alloc((size_t)N * 4);
    float* a_d2   = (float*)alloc((size_t)N * 4);
    float* scal   = (float*)alloc(3 * 4);

    hipMemsetAsync(d_ws, 0, zbytes, stream);

    pre_kernel<<<NCHUNK, 256, 0, stream>>>(ea, dstp, E, sum_ea, cnt, W1, Wt_hi, Wt_lo, NBUCK);
    soff_kernel<<<NBUCK, 256, 0, stream>>>(cnt, NBUCK, NCHUNK, bcount, poff);
    bscan_kernel<<<1, 1024, 0, stream>>>(bcount, NBUCK, E, bbase, row + N,
                                         sum_ea, W_edge1, att_edge1, W_edge2, att_edge2, scal);
    stage_kernel<<<NCHUNK, 256, 0, stream>>>(srcp, dstp, ea, E, cnt, poff, bbase,
                                             staging, NBUCK, NCHUNK);
    gemm1_mfma_kernel<<<(N + 63) / 64, 256, 0, stream>>>(x, Wt_hi, Wt_lo, att_src1, att_dst1,
                                                         h1b, a_s1, a_d1, N);
    bfin_kernel<<<NBUCK, 256, 0, stream>>>(staging, bbase, scal, a_s1, a_d1, row, sedge, sea2, N);
    agg1_kernel<<<(N + 31) / 32, 256, 0, stream>>>(row, sedge, scal, a_s1, a_d1, h1b,
                                                   bias1, W2, att_src2, att_dst2,
                                                   h2, a_s2, a_d2, N);
    agg2_kernel<<<(N + 31) / 32, 256, 0, stream>>>(row, sedge, sea2, scal, a_s2, a_d2, h2, bias2,
                                                   (float*)d_out, N);
}